// Round 3
// baseline (316.244 us; speedup 1.0000x reference)
//
#include <hip/hip_runtime.h>
#include <math.h>

#define N_NODES 50000
#define N_EDGES 800000
#define D_IN    64
#define H_HID   16
#define C_OUT   40
#define NBUCK   196      // ceil(50000/256) buckets of 256 nodes
#define NBLK    256      // edge slabs
#define EPB     3125     // N_EDGES / NBLK exactly

// ---- pass A: per-(block,bucket) histograms for src and dst keys (LDS only) ----
__global__ void bucket_count(const int* __restrict__ src, const int* __restrict__ dst,
                             int* __restrict__ partS, int* __restrict__ partD) {
    __shared__ int hS[NBUCK], hD[NBUCK];
    for (int i = threadIdx.x; i < NBUCK; i += blockDim.x) { hS[i] = 0; hD[i] = 0; }
    __syncthreads();
    int e0 = blockIdx.x * EPB;
    for (int e = e0 + threadIdx.x; e < e0 + EPB; e += blockDim.x) {
        atomicAdd(&hS[src[e] >> 8], 1);
        atomicAdd(&hD[dst[e] >> 8], 1);
    }
    __syncthreads();
    for (int i = threadIdx.x; i < NBUCK; i += blockDim.x) {
        partS[i * NBLK + blockIdx.x] = hS[i];   // [bucket][block] layout
        partD[i * NBLK + blockIdx.x] = hD[i];
    }
}

// ---- bucket base offsets (exclusive scan of bucket totals); block0=S, block1=D ----
__global__ void bucket_base(const int* __restrict__ partS, const int* __restrict__ partD,
                            int* __restrict__ baseS, int* __restrict__ baseD) {
    const int* part = blockIdx.x ? partD : partS;
    int* base = blockIdx.x ? baseD : baseS;
    __shared__ int tot[NBUCK];
    int b = threadIdx.x;
    if (b < NBUCK) {
        int s = 0;
        const int* row = part + b * NBLK;
        for (int k = 0; k < NBLK; ++k) s += row[k];
        tot[b] = s;
    }
    __syncthreads();
    if (threadIdx.x == 0) {
        int acc = 0;
        for (int i = 0; i < NBUCK; ++i) { int v = tot[i]; base[i] = acc; acc += v; }
        base[NBUCK] = acc;   // == N_EDGES
    }
}

// ---- pass B: scatter edges into bucket-grouped arrays; cursors via LDS atomics only ----
__global__ void bucket_scatter(const int* __restrict__ src, const int* __restrict__ dst,
                               const int* __restrict__ partS, const int* __restrict__ partD,
                               const int* __restrict__ baseS, const int* __restrict__ baseD,
                               unsigned int* __restrict__ packedD,
                               unsigned char* __restrict__ srcloc) {
    __shared__ int cS[NBUCK], cD[NBUCK];
    int blk = blockIdx.x;
    for (int b = threadIdx.x; b < NBUCK; b += blockDim.x) {
        int accS = baseS[b], accD = baseD[b];
        const int* rowS = partS + b * NBLK;
        const int* rowD = partD + b * NBLK;
        for (int k = 0; k < blk; ++k) { accS += rowS[k]; accD += rowD[k]; }
        cS[b] = accS; cD[b] = accD;
    }
    __syncthreads();
    int e0 = blk * EPB;
    for (int e = e0 + threadIdx.x; e < e0 + EPB; e += blockDim.x) {
        int s = src[e], d = dst[e];
        int pD = atomicAdd(&cD[d >> 8], 1);
        packedD[pD] = (unsigned)s | ((unsigned)(d & 255) << 16);
        int pS = atomicAdd(&cS[s >> 8], 1);
        srcloc[pS] = (unsigned char)(s & 255);
    }
}

// ---- per-bucket src-degree histogram -> dinv (one block per bucket) ----
__global__ void dinv_kernel(const unsigned char* __restrict__ srcloc,
                            const int* __restrict__ baseS, float* __restrict__ dinv) {
    __shared__ int hist[256];
    hist[threadIdx.x] = 0;
    __syncthreads();
    int beg = baseS[blockIdx.x], end = baseS[blockIdx.x + 1];
    for (int j = beg + threadIdx.x; j < end; j += blockDim.x)
        atomicAdd(&hist[srcloc[j]], 1);
    __syncthreads();
    int node = blockIdx.x * 256 + threadIdx.x;
    if (node < N_NODES) {
        int d = hist[threadIdx.x];
        dinv[node] = (d > 0) ? rsqrtf((float)d) : 0.0f;
    }
}

// ---- xw0 = x@W1[0]; sxw1 = dinv * (x@W1[1]) ----
__global__ void xw_kernel(const float* __restrict__ x, const float* __restrict__ W1,
                          const float* __restrict__ dinv,
                          float* __restrict__ xw0, float* __restrict__ sxw1) {
    __shared__ float sW[2 * D_IN * H_HID];
    for (int i = threadIdx.x; i < 2 * D_IN * H_HID; i += blockDim.x)
        sW[i] = W1[i];
    __syncthreads();
    int t = blockIdx.x * blockDim.x + threadIdx.x;
    if (t >= N_NODES * H_HID) return;
    int node = t >> 4;
    int f    = t & 15;
    const float* xr = x + node * D_IN;
    float a0 = 0.f, a1 = 0.f;
    #pragma unroll
    for (int d = 0; d < D_IN; ++d) {
        float xv = xr[d];
        a0 += xv * sW[d * H_HID + f];
        a1 += xv * sW[D_IN * H_HID + d * H_HID + f];
    }
    xw0[t]  = a0;
    sxw1[t] = dinv[node] * a1;
}

// ---- layer-1: LDS-accumulated aggregation + relu epilogue ----
__global__ void agg1_kernel(const unsigned int* __restrict__ packedD, const int* __restrict__ baseD,
                            const float* __restrict__ dinv, const float* __restrict__ sxw1,
                            const float* __restrict__ xw0, const float* __restrict__ b1,
                            float* __restrict__ h, float* __restrict__ sh) {
    __shared__ float acc[256 * H_HID];   // 16 KB
    __shared__ float sb[H_HID];
    for (int i = threadIdx.x; i < 256 * H_HID; i += blockDim.x) acc[i] = 0.f;
    if (threadIdx.x < H_HID) sb[threadIdx.x] = b1[threadIdx.x];
    __syncthreads();
    int bb = blockIdx.x;
    int beg = baseD[bb], end = baseD[bb + 1];
    int g = threadIdx.x >> 4, f = threadIdx.x & 15;    // 16 lanes per edge
    for (int j = beg + g; j < end; j += 16) {
        unsigned rec = packedD[j];
        int s  = rec & 0xFFFF;
        int dl = rec >> 16;
        atomicAdd(&acc[dl * H_HID + f], sxw1[s * H_HID + f]);
    }
    __syncthreads();
    for (int k = 0; k < 16; ++k) {
        int idx = k * 256 + threadIdx.x;       // coalesced, conflict-free
        int nl = idx >> 4, ff = idx & 15;
        int node = bb * 256 + nl;
        if (node < N_NODES) {
            float di = dinv[node];
            float v = xw0[node * H_HID + ff] - di * acc[idx] + sb[ff];
            v = fmaxf(v, 0.f);
            h[node * H_HID + ff]  = v;
            sh[node * H_HID + ff] = di * v;
        }
    }
}

// ---- layer-2: LDS aggregation + dual matmul + log_softmax ----
__global__ void agg2_kernel(const unsigned int* __restrict__ packedD, const int* __restrict__ baseD,
                            const float* __restrict__ dinv, const float* __restrict__ sh,
                            const float* __restrict__ h, const float* __restrict__ W2,
                            const float* __restrict__ b2, float* __restrict__ out) {
    __shared__ float acc[256 * H_HID];   // 16 KB
    __shared__ float sW0[H_HID * C_OUT], sW1[H_HID * C_OUT];
    __shared__ float sb[C_OUT];
    for (int i = threadIdx.x; i < 256 * H_HID; i += blockDim.x) acc[i] = 0.f;
    for (int i = threadIdx.x; i < H_HID * C_OUT; i += blockDim.x) {
        sW0[i] = W2[i];
        sW1[i] = W2[H_HID * C_OUT + i];
    }
    if (threadIdx.x < C_OUT) sb[threadIdx.x] = b2[threadIdx.x];
    __syncthreads();
    int bb = blockIdx.x;
    int beg = baseD[bb], end = baseD[bb + 1];
    int g = threadIdx.x >> 4, f = threadIdx.x & 15;
    for (int j = beg + g; j < end; j += 16) {
        unsigned rec = packedD[j];
        int s  = rec & 0xFFFF;
        int dl = rec >> 16;
        atomicAdd(&acc[dl * H_HID + f], sh[s * H_HID + f]);
    }
    __syncthreads();
    int node = bb * 256 + threadIdx.x;
    if (node >= N_NODES) return;
    float di = dinv[node];
    float hv[H_HID], t1[H_HID];
    #pragma unroll
    for (int i = 0; i < H_HID; ++i) {
        int ff = (threadIdx.x + i) & 15;               // stagger: avoid 32-way bank conflict
        t1[ff] = -di * acc[threadIdx.x * H_HID + ff];
    }
    const float4* h4 = (const float4*)(h + (size_t)node * H_HID);
    #pragma unroll
    for (int q = 0; q < 4; ++q) {
        float4 v = h4[q];
        hv[q * 4 + 0] = v.x; hv[q * 4 + 1] = v.y; hv[q * 4 + 2] = v.z; hv[q * 4 + 3] = v.w;
    }
    float o[C_OUT];
    float mx = -1e30f;
    #pragma unroll
    for (int c = 0; c < C_OUT; ++c) {
        float a = sb[c];
        #pragma unroll
        for (int ff = 0; ff < H_HID; ++ff) {
            a += hv[ff] * sW0[ff * C_OUT + c];
            a += t1[ff] * sW1[ff * C_OUT + c];
        }
        o[c] = a;
        mx = fmaxf(mx, a);
    }
    float sum = 0.f;
    #pragma unroll
    for (int c = 0; c < C_OUT; ++c) sum += expf(o[c] - mx);
    float lse = mx + logf(sum);
    #pragma unroll
    for (int c = 0; c < C_OUT; ++c) out[node * C_OUT + c] = o[c] - lse;
}

extern "C" void kernel_launch(void* const* d_in, const int* in_sizes, int n_in,
                              void* d_out, int out_size, void* d_ws, size_t ws_size,
                              hipStream_t stream) {
    const float* x   = (const float*)d_in[0];
    const int*   ei  = (const int*)d_in[1];
    const float* W1  = (const float*)d_in[2];
    const float* b1  = (const float*)d_in[3];
    const float* W2  = (const float*)d_in[4];
    const float* b2  = (const float*)d_in[5];
    float* out = (float*)d_out;

    const int* src = ei;            // edge_index[0]
    const int* dst = ei + N_EDGES;  // edge_index[1]

    // workspace layout (all 4-byte units unless noted)
    int* partS = (int*)d_ws;                                   // NBUCK*NBLK
    int* partD = partS + NBUCK * NBLK;                         // NBUCK*NBLK
    int* baseS = partD + NBUCK * NBLK;                         // NBUCK+1 (pad 256)
    int* baseD = baseS + 256;                                  // NBUCK+1 (pad 256)
    unsigned int*  packedD = (unsigned int*)(baseD + 256);     // E
    unsigned char* srcloc  = (unsigned char*)(packedD + N_EDGES); // E bytes (pad to int)
    float* dinv = (float*)(srcloc + ((N_EDGES + 3) & ~3));     // N
    float* xw0  = dinv + N_NODES;                              // N*16
    float* sxw1 = xw0  + (size_t)N_NODES * H_HID;              // N*16
    float* h    = sxw1 + (size_t)N_NODES * H_HID;              // N*16
    float* sh   = h    + (size_t)N_NODES * H_HID;              // N*16

    const int B = 256;
    bucket_count<<<NBLK, B, 0, stream>>>(src, dst, partS, partD);
    bucket_base<<<2, B, 0, stream>>>(partS, partD, baseS, baseD);
    bucket_scatter<<<NBLK, B, 0, stream>>>(src, dst, partS, partD, baseS, baseD, packedD, srcloc);
    dinv_kernel<<<NBUCK, B, 0, stream>>>(srcloc, baseS, dinv);
    xw_kernel<<<(N_NODES * H_HID + B - 1) / B, B, 0, stream>>>(x, W1, dinv, xw0, sxw1);
    agg1_kernel<<<NBUCK, B, 0, stream>>>(packedD, baseD, dinv, sxw1, xw0, b1, h, sh);
    agg2_kernel<<<NBUCK, B, 0, stream>>>(packedD, baseD, dinv, sh, h, W2, b2, out);
}

// Round 4
// 292.417 us; speedup vs baseline: 1.0815x; 1.0815x over previous
//
#include <hip/hip_runtime.h>
#include <math.h>

#define N_NODES 50000
#define N_EDGES 800000
#define D_IN    64
#define H_HID   16
#define C_OUT   40

#define BSH     7                                  // 128 nodes per bucket
#define BNODES  128
#define BMASK   127
#define NBUCK   ((N_NODES + BNODES - 1) / BNODES)  // 391
#define NBUCKP  400                                // padded stride for part arrays
#define NBLK    256                                // edge slabs
#define EPB     (N_EDGES / NBLK)                   // 3125 exact

// ---- pass A: per-(block,bucket) histograms, LDS only; layout part[block][bucket] ----
__global__ void bucket_count(const int* __restrict__ src, const int* __restrict__ dst,
                             int* __restrict__ partS, int* __restrict__ partD) {
    __shared__ int hS[NBUCK], hD[NBUCK];
    for (int i = threadIdx.x; i < NBUCK; i += blockDim.x) { hS[i] = 0; hD[i] = 0; }
    __syncthreads();
    int e0 = blockIdx.x * EPB;
    for (int e = e0 + threadIdx.x; e < e0 + EPB; e += blockDim.x) {
        atomicAdd(&hS[src[e] >> BSH], 1);
        atomicAdd(&hD[dst[e] >> BSH], 1);
    }
    __syncthreads();
    for (int i = threadIdx.x; i < NBUCK; i += blockDim.x) {
        partS[blockIdx.x * NBUCKP + i] = hS[i];
        partD[blockIdx.x * NBUCKP + i] = hD[i];
    }
}

// ---- bucket base offsets: column sums + serial exclusive scan (trivial size) ----
__global__ void bucket_base(const int* __restrict__ partS, const int* __restrict__ partD,
                            int* __restrict__ baseS, int* __restrict__ baseD) {
    const int* part = blockIdx.x ? partD : partS;
    int* base = blockIdx.x ? baseD : baseS;
    __shared__ int tot[NBUCK];
    int b = threadIdx.x;
    if (b < NBUCK) {
        int s = 0;
        for (int k = 0; k < NBLK; ++k) s += part[k * NBUCKP + b];   // coalesced across b
        tot[b] = s;
    }
    __syncthreads();
    if (threadIdx.x == 0) {
        int acc = 0;
        for (int i = 0; i < NBUCK; ++i) { base[i] = acc; acc += tot[i]; }
        base[NBUCK] = acc;   // == N_EDGES
    }
}

// ---- pass B: scatter into bucket-grouped arrays; cursors rebuilt coalesced, LDS atomics only ----
__global__ void bucket_scatter(const int* __restrict__ src, const int* __restrict__ dst,
                               const int* __restrict__ partS, const int* __restrict__ partD,
                               const int* __restrict__ baseS, const int* __restrict__ baseD,
                               unsigned int* __restrict__ packedD,
                               unsigned char* __restrict__ srcloc) {
    __shared__ int cS[NBUCK], cD[NBUCK];
    int blk = blockIdx.x;
    for (int b = threadIdx.x; b < NBUCK; b += blockDim.x) {
        int aS = baseS[b], aD = baseD[b];
        for (int k = 0; k < blk; ++k) {
            aS += partS[k * NBUCKP + b];   // coalesced across threads
            aD += partD[k * NBUCKP + b];
        }
        cS[b] = aS; cD[b] = aD;
    }
    __syncthreads();
    int e0 = blk * EPB;
    for (int e = e0 + threadIdx.x; e < e0 + EPB; e += blockDim.x) {
        int s = src[e], d = dst[e];
        int pD = atomicAdd(&cD[d >> BSH], 1);
        packedD[pD] = (unsigned)s | ((unsigned)(d & BMASK) << 16);
        int pS = atomicAdd(&cS[s >> BSH], 1);
        srcloc[pS] = (unsigned char)(s & BMASK);
    }
}

// ---- per-bucket src-degree histogram -> dinv ----
__global__ void dinv_kernel(const unsigned char* __restrict__ srcloc,
                            const int* __restrict__ baseS, float* __restrict__ dinv) {
    __shared__ int hist[BNODES];
    if (threadIdx.x < BNODES) hist[threadIdx.x] = 0;
    __syncthreads();
    int beg = baseS[blockIdx.x], end = baseS[blockIdx.x + 1];
    for (int j = beg + threadIdx.x; j < end; j += blockDim.x)
        atomicAdd(&hist[srcloc[j]], 1);
    __syncthreads();
    int node = blockIdx.x * BNODES + threadIdx.x;
    if (threadIdx.x < BNODES && node < N_NODES) {
        int d = hist[threadIdx.x];
        dinv[node] = (d > 0) ? rsqrtf((float)d) : 0.0f;
    }
}

// ---- xw0 = x@W1[0]; sxw1 = dinv * (x@W1[1]); x staged in LDS (padded rows) ----
__global__ void xw_kernel(const float* __restrict__ x, const float* __restrict__ W1,
                          const float* __restrict__ dinv,
                          float* __restrict__ xw0, float* __restrict__ sxw1) {
    __shared__ float sW[2 * D_IN * H_HID];   // 8 KB
    __shared__ float sx[16 * 65];            // 16 x-rows, padded to kill bank conflicts
    for (int i = threadIdx.x; i < 2 * D_IN * H_HID; i += 256) sW[i] = W1[i];
    int nbase = blockIdx.x * 16;
    for (int i = threadIdx.x; i < 16 * D_IN; i += 256) {
        int r = i >> 6, c = i & 63;
        sx[r * 65 + c] = x[(size_t)(nbase + r) * D_IN + c];   // coalesced
    }
    __syncthreads();
    int nl = threadIdx.x >> 4, f = threadIdx.x & 15;
    int node = nbase + nl;                    // N = 3125*16 exactly, no guard
    float a0 = 0.f, a1 = 0.f;
    #pragma unroll
    for (int d = 0; d < D_IN; ++d) {
        float xv = sx[nl * 65 + d];
        a0 += xv * sW[d * H_HID + f];
        a1 += xv * sW[D_IN * H_HID + d * H_HID + f];
    }
    int t = node * H_HID + f;
    xw0[t]  = a0;
    sxw1[t] = dinv[node] * a1;
}

// ---- layer-1: LDS-accumulated aggregation + relu epilogue (512 thr, 32 edges in flight) ----
__global__ void agg1_kernel(const unsigned int* __restrict__ packedD, const int* __restrict__ baseD,
                            const float* __restrict__ dinv, const float* __restrict__ sxw1,
                            const float* __restrict__ xw0, const float* __restrict__ b1,
                            float* __restrict__ h, float* __restrict__ sh) {
    __shared__ float acc[BNODES * H_HID];   // 8 KB
    __shared__ float sb[H_HID];
    for (int i = threadIdx.x; i < BNODES * H_HID; i += blockDim.x) acc[i] = 0.f;
    if (threadIdx.x < H_HID) sb[threadIdx.x] = b1[threadIdx.x];
    __syncthreads();
    int bb = blockIdx.x;
    int beg = baseD[bb], end = baseD[bb + 1];
    int g = threadIdx.x >> 4, f = threadIdx.x & 15;
    for (int j = beg + g; j < end; j += 32) {
        unsigned rec = packedD[j];
        int s  = rec & 0xFFFF;
        int dl = rec >> 16;
        atomicAdd(&acc[dl * H_HID + f], sxw1[s * H_HID + f]);
    }
    __syncthreads();
    #pragma unroll
    for (int k = 0; k < 4; ++k) {
        int idx = k * 512 + threadIdx.x;
        int nl = idx >> 4, ff = idx & 15;
        int node = bb * BNODES + nl;
        if (node < N_NODES) {
            float di = dinv[node];
            float v = xw0[node * H_HID + ff] - di * acc[idx] + sb[ff];
            v = fmaxf(v, 0.f);
            h[node * H_HID + ff]  = v;
            sh[node * H_HID + ff] = di * v;
        }
    }
}

// ---- layer-2: LDS aggregation + dual matmul + log_softmax; all 512 threads in epilogue ----
__global__ void agg2_kernel(const unsigned int* __restrict__ packedD, const int* __restrict__ baseD,
                            const float* __restrict__ dinv, const float* __restrict__ sh,
                            const float* __restrict__ h, const float* __restrict__ W2,
                            const float* __restrict__ b2, float* __restrict__ out) {
    __shared__ float acc[BNODES * H_HID];   // 8 KB
    __shared__ float sW0[H_HID * C_OUT], sW1[H_HID * C_OUT];
    __shared__ float sb[C_OUT];
    for (int i = threadIdx.x; i < BNODES * H_HID; i += blockDim.x) acc[i] = 0.f;
    for (int i = threadIdx.x; i < H_HID * C_OUT; i += blockDim.x) {
        sW0[i] = W2[i];
        sW1[i] = W2[H_HID * C_OUT + i];
    }
    if (threadIdx.x < C_OUT) sb[threadIdx.x] = b2[threadIdx.x];
    __syncthreads();
    int bb = blockIdx.x;
    int beg = baseD[bb], end = baseD[bb + 1];
    int g = threadIdx.x >> 4, f = threadIdx.x & 15;
    for (int j = beg + g; j < end; j += 32) {
        unsigned rec = packedD[j];
        int s  = rec & 0xFFFF;
        int dl = rec >> 16;
        atomicAdd(&acc[dl * H_HID + f], sh[s * H_HID + f]);
    }
    __syncthreads();
    // epilogue: 4 threads per node, 10 classes each
    int nl = threadIdx.x >> 2, cq = threadIdx.x & 3;
    int node = bb * BNODES + nl;
    if (node >= N_NODES) return;
    float di = dinv[node];
    float hv[H_HID], t1[H_HID];
    const float4* h4 = (const float4*)(h + (size_t)node * H_HID);
    #pragma unroll
    for (int q = 0; q < 4; ++q) {
        float4 v = h4[q];
        hv[q*4+0] = v.x; hv[q*4+1] = v.y; hv[q*4+2] = v.z; hv[q*4+3] = v.w;
    }
    #pragma unroll
    for (int k = 0; k < H_HID; ++k) {
        int ff = (k + nl) & 15;                     // stagger banks
        t1[ff] = -di * acc[nl * H_HID + ff];
    }
    float o[10];
    float mx = -1e30f;
    #pragma unroll
    for (int i = 0; i < 10; ++i) {
        int c = cq * 10 + i;
        float a = sb[c];
        #pragma unroll
        for (int ff = 0; ff < H_HID; ++ff)
            a += hv[ff] * sW0[ff * C_OUT + c] + t1[ff] * sW1[ff * C_OUT + c];
        o[i] = a;
        mx = fmaxf(mx, a);
    }
    mx = fmaxf(mx, __shfl_xor(mx, 1));
    mx = fmaxf(mx, __shfl_xor(mx, 2));
    float sum = 0.f;
    #pragma unroll
    for (int i = 0; i < 10; ++i) sum += expf(o[i] - mx);
    sum += __shfl_xor(sum, 1);
    sum += __shfl_xor(sum, 2);
    float lse = mx + logf(sum);
    #pragma unroll
    for (int i = 0; i < 10; ++i) out[(size_t)node * C_OUT + cq * 10 + i] = o[i] - lse;
}

extern "C" void kernel_launch(void* const* d_in, const int* in_sizes, int n_in,
                              void* d_out, int out_size, void* d_ws, size_t ws_size,
                              hipStream_t stream) {
    const float* x   = (const float*)d_in[0];
    const int*   ei  = (const int*)d_in[1];
    const float* W1  = (const float*)d_in[2];
    const float* b1  = (const float*)d_in[3];
    const float* W2  = (const float*)d_in[4];
    const float* b2  = (const float*)d_in[5];
    float* out = (float*)d_out;

    const int* src = ei;            // edge_index[0]
    const int* dst = ei + N_EDGES;  // edge_index[1]

    // workspace layout
    int* partS = (int*)d_ws;                                    // NBLK*NBUCKP
    int* partD = partS + NBLK * NBUCKP;                         // NBLK*NBUCKP
    int* baseS = partD + NBLK * NBUCKP;                         // NBUCK+1 (pad 512)
    int* baseD = baseS + 512;                                   // NBUCK+1 (pad 512)
    unsigned int*  packedD = (unsigned int*)(baseD + 512);      // E
    unsigned char* srcloc  = (unsigned char*)(packedD + N_EDGES); // E bytes (E%4==0)
    float* dinv = (float*)(srcloc + N_EDGES);                   // N
    float* xw0  = dinv + N_NODES;                               // N*16
    float* sxw1 = xw0  + (size_t)N_NODES * H_HID;               // N*16
    float* h    = sxw1 + (size_t)N_NODES * H_HID;               // N*16
    float* sh   = h    + (size_t)N_NODES * H_HID;               // N*16

    bucket_count  <<<NBLK, 256, 0, stream>>>(src, dst, partS, partD);
    bucket_base   <<<2, 512, 0, stream>>>(partS, partD, baseS, baseD);
    bucket_scatter<<<NBLK, 256, 0, stream>>>(src, dst, partS, partD, baseS, baseD, packedD, srcloc);
    dinv_kernel   <<<NBUCK, 256, 0, stream>>>(srcloc, baseS, dinv);
    xw_kernel     <<<N_NODES / 16, 256, 0, stream>>>(x, W1, dinv, xw0, sxw1);
    agg1_kernel   <<<NBUCK, 512, 0, stream>>>(packedD, baseD, dinv, sxw1, xw0, b1, h, sh);
    agg2_kernel   <<<NBUCK, 512, 0, stream>>>(packedD, baseD, dinv, sh, h, W2, b2, out);
}

// Round 5
// 276.679 us; speedup vs baseline: 1.1430x; 1.0569x over previous
//
#include <hip/hip_runtime.h>
#include <math.h>

#define N_NODES 50000
#define N_EDGES 800000
#define D_IN    64
#define H_HID   16
#define C_OUT   40

#define BSH     7                                  // 128 nodes per bucket
#define BNODES  128
#define BMASK   127
#define NBUCK   ((N_NODES + BNODES - 1) / BNODES)  // 391
#define NBUCKP  400                                // padded stride for part arrays
#define NBLK    250                                // edge slabs
#define EPB     (N_EDGES / NBLK)                   // 3200 exact, 16B-aligned slab starts
#define EPB4    (EPB / 4)                          // 800 int4s per slab

// ---- pass A: per-(block,bucket) histograms, LDS only; layout part[block][bucket] ----
__global__ void bucket_count(const int* __restrict__ src, const int* __restrict__ dst,
                             int* __restrict__ partS, int* __restrict__ partD) {
    __shared__ int hS[NBUCK], hD[NBUCK];
    for (int i = threadIdx.x; i < NBUCK; i += blockDim.x) { hS[i] = 0; hD[i] = 0; }
    __syncthreads();
    const int4* s4 = (const int4*)(src + blockIdx.x * EPB);
    const int4* d4 = (const int4*)(dst + blockIdx.x * EPB);
    for (int k = threadIdx.x; k < EPB4; k += blockDim.x) {
        int4 s = s4[k], d = d4[k];
        atomicAdd(&hS[s.x >> BSH], 1); atomicAdd(&hS[s.y >> BSH], 1);
        atomicAdd(&hS[s.z >> BSH], 1); atomicAdd(&hS[s.w >> BSH], 1);
        atomicAdd(&hD[d.x >> BSH], 1); atomicAdd(&hD[d.y >> BSH], 1);
        atomicAdd(&hD[d.z >> BSH], 1); atomicAdd(&hD[d.w >> BSH], 1);
    }
    __syncthreads();
    for (int i = threadIdx.x; i < NBUCK; i += blockDim.x) {
        partS[blockIdx.x * NBUCKP + i] = hS[i];
        partD[blockIdx.x * NBUCKP + i] = hD[i];
    }
}

// ---- bucket base offsets: column sums + serial exclusive scan ----
__global__ void bucket_base(const int* __restrict__ partS, const int* __restrict__ partD,
                            int* __restrict__ baseS, int* __restrict__ baseD) {
    const int* part = blockIdx.x ? partD : partS;
    int* base = blockIdx.x ? baseD : baseS;
    __shared__ int tot[NBUCK];
    int b = threadIdx.x;
    if (b < NBUCK) {
        int s = 0;
        for (int k = 0; k < NBLK; ++k) s += part[k * NBUCKP + b];   // coalesced across b
        tot[b] = s;
    }
    __syncthreads();
    if (threadIdx.x == 0) {
        int acc = 0;
        for (int i = 0; i < NBUCK; ++i) { base[i] = acc; acc += tot[i]; }
        base[NBUCK] = acc;   // == N_EDGES
    }
}

// ---- pass B: scatter into bucket-grouped arrays; LDS cursors, int4 edge loads ----
__global__ void bucket_scatter(const int* __restrict__ src, const int* __restrict__ dst,
                               const int* __restrict__ partS, const int* __restrict__ partD,
                               const int* __restrict__ baseS, const int* __restrict__ baseD,
                               unsigned int* __restrict__ packedD,
                               unsigned char* __restrict__ srcloc) {
    __shared__ int cS[NBUCK], cD[NBUCK];
    int blk = blockIdx.x;
    for (int b = threadIdx.x; b < NBUCK; b += blockDim.x) {
        int aS = baseS[b], aD = baseD[b];
        for (int k = 0; k < blk; ++k) {
            aS += partS[k * NBUCKP + b];   // coalesced across threads
            aD += partD[k * NBUCKP + b];
        }
        cS[b] = aS; cD[b] = aD;
    }
    __syncthreads();
    const int4* s4 = (const int4*)(src + blk * EPB);
    const int4* d4 = (const int4*)(dst + blk * EPB);
    for (int k = threadIdx.x; k < EPB4; k += blockDim.x) {
        int4 sv = s4[k], dv = d4[k];
        int ss[4] = { sv.x, sv.y, sv.z, sv.w };
        int dd[4] = { dv.x, dv.y, dv.z, dv.w };
        #pragma unroll
        for (int u = 0; u < 4; ++u) {
            int s = ss[u], d = dd[u];
            int pD = atomicAdd(&cD[d >> BSH], 1);
            packedD[pD] = (unsigned)s | ((unsigned)(d & BMASK) << 16);
            int pS = atomicAdd(&cS[s >> BSH], 1);
            srcloc[pS] = (unsigned char)(s & BMASK);
        }
    }
}

// ---- per-bucket src-degree histogram -> dinv ----
__global__ void dinv_kernel(const unsigned char* __restrict__ srcloc,
                            const int* __restrict__ baseS, float* __restrict__ dinv) {
    __shared__ int hist[BNODES];
    if (threadIdx.x < BNODES) hist[threadIdx.x] = 0;
    __syncthreads();
    int beg = baseS[blockIdx.x], end = baseS[blockIdx.x + 1];
    for (int j = beg + threadIdx.x; j < end; j += blockDim.x)
        atomicAdd(&hist[srcloc[j]], 1);
    __syncthreads();
    int node = blockIdx.x * BNODES + threadIdx.x;
    if (threadIdx.x < BNODES && node < N_NODES) {
        int d = hist[threadIdx.x];
        dinv[node] = (d > 0) ? rsqrtf((float)d) : 0.0f;
    }
}

// ---- xw0 = x@W1[0]; sxw1 = dinv * (x@W1[1]); x staged in LDS ----
__global__ void xw_kernel(const float* __restrict__ x, const float* __restrict__ W1,
                          const float* __restrict__ dinv,
                          float* __restrict__ xw0, float* __restrict__ sxw1) {
    __shared__ float sW[2 * D_IN * H_HID];   // 8 KB
    __shared__ float sx[16 * 65];
    for (int i = threadIdx.x; i < 2 * D_IN * H_HID; i += 256) sW[i] = W1[i];
    int nbase = blockIdx.x * 16;
    for (int i = threadIdx.x; i < 16 * D_IN; i += 256) {
        int r = i >> 6, c = i & 63;
        sx[r * 65 + c] = x[(size_t)(nbase + r) * D_IN + c];
    }
    __syncthreads();
    int nl = threadIdx.x >> 4, f = threadIdx.x & 15;
    int node = nbase + nl;                    // N = 3125*16 exactly
    float a0 = 0.f, a1 = 0.f;
    #pragma unroll
    for (int d = 0; d < D_IN; ++d) {
        float xv = sx[nl * 65 + d];
        a0 += xv * sW[d * H_HID + f];
        a1 += xv * sW[D_IN * H_HID + d * H_HID + f];
    }
    int t = node * H_HID + f;
    xw0[t]  = a0;
    sxw1[t] = dinv[node] * a1;
}

// ---- layer-1: LDS aggregation, unroll-8 MLP, relu epilogue ----
__global__ void agg1_kernel(const unsigned int* __restrict__ packedD, const int* __restrict__ baseD,
                            const float* __restrict__ dinv, const float* __restrict__ sxw1,
                            const float* __restrict__ xw0, const float* __restrict__ b1,
                            float* __restrict__ h, float* __restrict__ sh) {
    __shared__ float acc[BNODES * H_HID];   // 8 KB
    __shared__ float sb[H_HID];
    for (int i = threadIdx.x; i < BNODES * H_HID; i += 512) acc[i] = 0.f;
    if (threadIdx.x < H_HID) sb[threadIdx.x] = b1[threadIdx.x];
    __syncthreads();
    int bb = blockIdx.x;
    int beg = baseD[bb], end = baseD[bb + 1];
    const int G = 32;                                 // 512/16 groups
    int g = threadIdx.x >> 4, f = threadIdx.x & 15;
    int j = beg + g;
    for (; j + 7 * G < end; j += 8 * G) {             // batch-of-8: 8 chains in flight
        unsigned recs[8];
        #pragma unroll
        for (int u = 0; u < 8; ++u) recs[u] = packedD[j + u * G];
        float vals[8];
        #pragma unroll
        for (int u = 0; u < 8; ++u) vals[u] = sxw1[(recs[u] & 0xFFFF) * H_HID + f];
        #pragma unroll
        for (int u = 0; u < 8; ++u) atomicAdd(&acc[(recs[u] >> 16) * H_HID + f], vals[u]);
    }
    for (; j < end; j += G) {
        unsigned rec = packedD[j];
        atomicAdd(&acc[(rec >> 16) * H_HID + f], sxw1[(rec & 0xFFFF) * H_HID + f]);
    }
    __syncthreads();
    #pragma unroll
    for (int k = 0; k < 4; ++k) {
        int idx = k * 512 + threadIdx.x;
        int nl = idx >> 4, ff = idx & 15;
        int node = bb * BNODES + nl;
        if (node < N_NODES) {
            float di = dinv[node];
            float v = xw0[node * H_HID + ff] - di * acc[idx] + sb[ff];
            v = fmaxf(v, 0.f);
            h[node * H_HID + ff]  = v;
            sh[node * H_HID + ff] = di * v;
        }
    }
}

// ---- layer-2: LDS aggregation (unroll-8) + dual matmul + log_softmax ----
__global__ void agg2_kernel(const unsigned int* __restrict__ packedD, const int* __restrict__ baseD,
                            const float* __restrict__ dinv, const float* __restrict__ sh,
                            const float* __restrict__ h, const float* __restrict__ W2,
                            const float* __restrict__ b2, float* __restrict__ out) {
    __shared__ float acc[BNODES * H_HID];   // 8 KB
    __shared__ float sW0[H_HID * C_OUT], sW1[H_HID * C_OUT];
    __shared__ float sb[C_OUT];
    for (int i = threadIdx.x; i < BNODES * H_HID; i += 512) acc[i] = 0.f;
    for (int i = threadIdx.x; i < H_HID * C_OUT; i += 512) {
        sW0[i] = W2[i];
        sW1[i] = W2[H_HID * C_OUT + i];
    }
    if (threadIdx.x < C_OUT) sb[threadIdx.x] = b2[threadIdx.x];
    __syncthreads();
    int bb = blockIdx.x;
    int beg = baseD[bb], end = baseD[bb + 1];
    const int G = 32;
    int g = threadIdx.x >> 4, f = threadIdx.x & 15;
    int j = beg + g;
    for (; j + 7 * G < end; j += 8 * G) {
        unsigned recs[8];
        #pragma unroll
        for (int u = 0; u < 8; ++u) recs[u] = packedD[j + u * G];
        float vals[8];
        #pragma unroll
        for (int u = 0; u < 8; ++u) vals[u] = sh[(recs[u] & 0xFFFF) * H_HID + f];
        #pragma unroll
        for (int u = 0; u < 8; ++u) atomicAdd(&acc[(recs[u] >> 16) * H_HID + f], vals[u]);
    }
    for (; j < end; j += G) {
        unsigned rec = packedD[j];
        atomicAdd(&acc[(rec >> 16) * H_HID + f], sh[(rec & 0xFFFF) * H_HID + f]);
    }
    __syncthreads();
    // epilogue: 4 threads per node, 10 classes each
    int nl = threadIdx.x >> 2, cq = threadIdx.x & 3;
    int node = bb * BNODES + nl;
    if (node >= N_NODES) return;
    float di = dinv[node];
    float hv[H_HID], t1[H_HID];
    const float4* h4 = (const float4*)(h + (size_t)node * H_HID);
    #pragma unroll
    for (int q = 0; q < 4; ++q) {
        float4 v = h4[q];
        hv[q*4+0] = v.x; hv[q*4+1] = v.y; hv[q*4+2] = v.z; hv[q*4+3] = v.w;
    }
    #pragma unroll
    for (int k = 0; k < H_HID; ++k) {
        int ff = (k + nl) & 15;                     // stagger banks
        t1[ff] = -di * acc[nl * H_HID + ff];
    }
    float o[10];
    float mx = -1e30f;
    #pragma unroll
    for (int i = 0; i < 10; ++i) {
        int c = cq * 10 + i;
        float a = sb[c];
        #pragma unroll
        for (int ff = 0; ff < H_HID; ++ff)
            a += hv[ff] * sW0[ff * C_OUT + c] + t1[ff] * sW1[ff * C_OUT + c];
        o[i] = a;
        mx = fmaxf(mx, a);
    }
    mx = fmaxf(mx, __shfl_xor(mx, 1));
    mx = fmaxf(mx, __shfl_xor(mx, 2));
    float sum = 0.f;
    #pragma unroll
    for (int i = 0; i < 10; ++i) sum += expf(o[i] - mx);
    sum += __shfl_xor(sum, 1);
    sum += __shfl_xor(sum, 2);
    float lse = mx + logf(sum);
    #pragma unroll
    for (int i = 0; i < 10; ++i) out[(size_t)node * C_OUT + cq * 10 + i] = o[i] - lse;
}

extern "C" void kernel_launch(void* const* d_in, const int* in_sizes, int n_in,
                              void* d_out, int out_size, void* d_ws, size_t ws_size,
                              hipStream_t stream) {
    const float* x   = (const float*)d_in[0];
    const int*   ei  = (const int*)d_in[1];
    const float* W1  = (const float*)d_in[2];
    const float* b1  = (const float*)d_in[3];
    const float* W2  = (const float*)d_in[4];
    const float* b2  = (const float*)d_in[5];
    float* out = (float*)d_out;

    const int* src = ei;            // edge_index[0]
    const int* dst = ei + N_EDGES;  // edge_index[1]

    // workspace layout
    int* partS = (int*)d_ws;                                    // NBLK*NBUCKP
    int* partD = partS + NBLK * NBUCKP;                         // NBLK*NBUCKP
    int* baseS = partD + NBLK * NBUCKP;                         // NBUCK+1 (pad 512)
    int* baseD = baseS + 512;                                   // NBUCK+1 (pad 512)
    unsigned int*  packedD = (unsigned int*)(baseD + 512);      // E
    unsigned char* srcloc  = (unsigned char*)(packedD + N_EDGES); // E bytes (E%4==0)
    float* dinv = (float*)(srcloc + N_EDGES);                   // N
    float* xw0  = dinv + N_NODES;                               // N*16
    float* sxw1 = xw0  + (size_t)N_NODES * H_HID;               // N*16
    float* h    = sxw1 + (size_t)N_NODES * H_HID;               // N*16
    float* sh   = h    + (size_t)N_NODES * H_HID;               // N*16

    bucket_count  <<<NBLK, 256, 0, stream>>>(src, dst, partS, partD);
    bucket_base   <<<2, 512, 0, stream>>>(partS, partD, baseS, baseD);
    bucket_scatter<<<NBLK, 512, 0, stream>>>(src, dst, partS, partD, baseS, baseD, packedD, srcloc);
    dinv_kernel   <<<NBUCK, 256, 0, stream>>>(srcloc, baseS, dinv);
    xw_kernel     <<<N_NODES / 16, 256, 0, stream>>>(x, W1, dinv, xw0, sxw1);
    agg1_kernel   <<<NBUCK, 512, 0, stream>>>(packedD, baseD, dinv, sxw1, xw0, b1, h, sh);
    agg2_kernel   <<<NBUCK, 512, 0, stream>>>(packedD, baseD, dinv, sh, h, W2, b2, out);
}

// Round 6
// 159.115 us; speedup vs baseline: 1.9875x; 1.7389x over previous
//
#include <hip/hip_runtime.h>
#include <math.h>

#define N_NODES 50000
#define N_EDGES 800000
#define D_IN    64
#define H_HID   16
#define C_OUT   40

#define BSH     7                                  // 128 nodes per bucket
#define BNODES  128
#define BMASK   127
#define NBUCK   ((N_NODES + BNODES - 1) / BNODES)  // 391
#define NBUCKP  400                                // padded stride for part arrays
#define NBLK    250                                // edge slabs
#define EPB     (N_EDGES / NBLK)                   // 3200 exact, 16B-aligned
#define EPB4    (EPB / 4)                          // 800 int4s per slab

// ---- pass A: per-(block,bucket) histograms, LDS only; part[block][bucket] ----
__global__ void bucket_count(const int* __restrict__ src, const int* __restrict__ dst,
                             int* __restrict__ partS, int* __restrict__ partD) {
    __shared__ int hS[NBUCK], hD[NBUCK];
    for (int i = threadIdx.x; i < NBUCK; i += blockDim.x) { hS[i] = 0; hD[i] = 0; }
    __syncthreads();
    const int4* s4 = (const int4*)(src + blockIdx.x * EPB);
    const int4* d4 = (const int4*)(dst + blockIdx.x * EPB);
    for (int k = threadIdx.x; k < EPB4; k += blockDim.x) {
        int4 s = s4[k], d = d4[k];
        atomicAdd(&hS[s.x >> BSH], 1); atomicAdd(&hS[s.y >> BSH], 1);
        atomicAdd(&hS[s.z >> BSH], 1); atomicAdd(&hS[s.w >> BSH], 1);
        atomicAdd(&hD[d.x >> BSH], 1); atomicAdd(&hD[d.y >> BSH], 1);
        atomicAdd(&hD[d.z >> BSH], 1); atomicAdd(&hD[d.w >> BSH], 1);
    }
    __syncthreads();
    for (int i = threadIdx.x; i < NBUCK; i += blockDim.x) {
        partS[blockIdx.x * NBUCKP + i] = hS[i];
        partD[blockIdx.x * NBUCKP + i] = hD[i];
    }
}

// ---- bucket base offsets ----
__global__ void bucket_base(const int* __restrict__ partS, const int* __restrict__ partD,
                            int* __restrict__ baseS, int* __restrict__ baseD) {
    const int* part = blockIdx.x ? partD : partS;
    int* base = blockIdx.x ? baseD : baseS;
    __shared__ int tot[NBUCK];
    int b = threadIdx.x;
    if (b < NBUCK) {
        int s = 0;
        for (int k = 0; k < NBLK; ++k) s += part[k * NBUCKP + b];
        tot[b] = s;
    }
    __syncthreads();
    if (threadIdx.x == 0) {
        int acc = 0;
        for (int i = 0; i < NBUCK; ++i) { base[i] = acc; acc += tot[i]; }
        base[NBUCK] = acc;   // == N_EDGES
    }
}

// ---- pass B: scatter edges into bucket-grouped arrays; LDS cursors only ----
__global__ void bucket_scatter(const int* __restrict__ src, const int* __restrict__ dst,
                               const int* __restrict__ partS, const int* __restrict__ partD,
                               const int* __restrict__ baseS, const int* __restrict__ baseD,
                               unsigned int* __restrict__ packedD,
                               unsigned char* __restrict__ srcloc) {
    __shared__ int cS[NBUCK], cD[NBUCK];
    int blk = blockIdx.x;
    for (int b = threadIdx.x; b < NBUCK; b += blockDim.x) {
        int aS = baseS[b], aD = baseD[b];
        for (int k = 0; k < blk; ++k) {
            aS += partS[k * NBUCKP + b];
            aD += partD[k * NBUCKP + b];
        }
        cS[b] = aS; cD[b] = aD;
    }
    __syncthreads();
    const int4* s4 = (const int4*)(src + blk * EPB);
    const int4* d4 = (const int4*)(dst + blk * EPB);
    for (int k = threadIdx.x; k < EPB4; k += blockDim.x) {
        int4 sv = s4[k], dv = d4[k];
        int ss[4] = { sv.x, sv.y, sv.z, sv.w };
        int dd[4] = { dv.x, dv.y, dv.z, dv.w };
        #pragma unroll
        for (int u = 0; u < 4; ++u) {
            int s = ss[u], d = dd[u];
            int pD = atomicAdd(&cD[d >> BSH], 1);
            packedD[pD] = (unsigned)s | ((unsigned)(d & BMASK) << 16);
            int pS = atomicAdd(&cS[s >> BSH], 1);
            srcloc[pS] = (unsigned char)(s & BMASK);
        }
    }
}

// ---- per-bucket counting sort -> per-node CSR (col, rowptr) + src-degree -> dinv ----
__global__ void csr_build(const unsigned int* __restrict__ packedD, const int* __restrict__ baseD,
                          const unsigned char* __restrict__ srcloc, const int* __restrict__ baseS,
                          int* __restrict__ col, int* __restrict__ rowptr,
                          float* __restrict__ dinv) {
    __shared__ int hist[BNODES], scanv[BNODES], cur[BNODES], shist[BNODES];
    int tid = threadIdx.x;
    if (tid < BNODES) { hist[tid] = 0; shist[tid] = 0; }
    __syncthreads();
    int bb = blockIdx.x;
    int begD = baseD[bb], endD = baseD[bb + 1];
    for (int j = begD + tid; j < endD; j += blockDim.x)
        atomicAdd(&hist[(packedD[j] >> 16) & BMASK], 1);
    int begS = baseS[bb], endS = baseS[bb + 1];
    for (int j = begS + tid; j < endS; j += blockDim.x)
        atomicAdd(&shist[srcloc[j]], 1);
    __syncthreads();
    if (tid == 0) {
        int acc = 0;
        for (int i = 0; i < BNODES; ++i) { scanv[i] = acc; acc += hist[i]; }
    }
    __syncthreads();
    if (tid < BNODES) {
        cur[tid] = scanv[tid];
        int node = bb * BNODES + tid;
        if (node < N_NODES) {
            rowptr[node] = begD + scanv[tid];
            int d = shist[tid];
            dinv[node] = (d > 0) ? rsqrtf((float)d) : 0.0f;
        }
    }
    if (bb == NBUCK - 1 && tid == 0) rowptr[N_NODES] = endD;   // == N_EDGES
    __syncthreads();
    for (int j = begD + tid; j < endD; j += blockDim.x) {
        unsigned rec = packedD[j];
        int dl = (rec >> 16) & BMASK;
        int pos = atomicAdd(&cur[dl], 1);
        col[begD + pos] = (int)(rec & 0xFFFF) | ((bb & 0) );   // src id (fits 16b)
    }
}

// ---- xw0 = x@W1[0]; sxw1 = dinv * (x@W1[1]) ----
__global__ void xw_kernel(const float* __restrict__ x, const float* __restrict__ W1,
                          const float* __restrict__ dinv,
                          float* __restrict__ xw0, float* __restrict__ sxw1) {
    __shared__ float sW[2 * D_IN * H_HID];   // 8 KB
    __shared__ float sx[16 * 65];
    for (int i = threadIdx.x; i < 2 * D_IN * H_HID; i += 256) sW[i] = W1[i];
    int nbase = blockIdx.x * 16;
    for (int i = threadIdx.x; i < 16 * D_IN; i += 256) {
        int r = i >> 6, c = i & 63;
        sx[r * 65 + c] = x[(size_t)(nbase + r) * D_IN + c];
    }
    __syncthreads();
    int nl = threadIdx.x >> 4, f = threadIdx.x & 15;
    int node = nbase + nl;                    // N = 3125*16 exactly
    float a0 = 0.f, a1 = 0.f;
    #pragma unroll
    for (int d = 0; d < D_IN; ++d) {
        float xv = sx[nl * 65 + d];
        a0 += xv * sW[d * H_HID + f];
        a1 += xv * sW[D_IN * H_HID + d * H_HID + f];
    }
    int t = node * H_HID + f;
    xw0[t]  = a0;
    sxw1[t] = dinv[node] * a1;
}

// ---- layer-1 gather: one wave per node; 4 edge-slots x 16 feats; no atomics ----
__global__ void gather1(const int* __restrict__ rowptr, const int* __restrict__ col,
                        const float* __restrict__ dinv, const float* __restrict__ sxw1,
                        const float* __restrict__ xw0, const float* __restrict__ b1,
                        float* __restrict__ h, float* __restrict__ sh) {
    int lane = threadIdx.x & 63;
    int wid  = threadIdx.x >> 6;
    int node = blockIdx.x * 8 + wid;          // 6250*8 = 50000 exact
    int slot = lane >> 4, f = lane & 15;
    int beg = rowptr[node], end = rowptr[node + 1];
    float acc = 0.f;
    int j = beg + slot;
    while (j + 4 < end) {                     // 2-deep: 8 gathers in flight per wave
        int s0 = col[j], s1 = col[j + 4];
        acc += sxw1[s0 * H_HID + f];
        acc += sxw1[s1 * H_HID + f];
        j += 8;
    }
    if (j < end) acc += sxw1[col[j] * H_HID + f];
    acc += __shfl_xor(acc, 16);
    acc += __shfl_xor(acc, 32);
    if (slot == 0) {
        float di = dinv[node];
        float v = xw0[node * H_HID + f] - di * acc + b1[f];
        v = fmaxf(v, 0.f);
        h[node * H_HID + f]  = v;
        sh[node * H_HID + f] = di * v;
    }
}

// ---- layer-2 gather + dual matmul + log_softmax: one wave per node ----
__global__ void gather2_out(const int* __restrict__ rowptr, const int* __restrict__ col,
                            const float* __restrict__ dinv, const float* __restrict__ sh,
                            const float* __restrict__ h, const float* __restrict__ W2,
                            const float* __restrict__ b2, float* __restrict__ out) {
    __shared__ float sW0[H_HID * C_OUT], sW1[H_HID * C_OUT], sb[C_OUT];
    for (int i = threadIdx.x; i < H_HID * C_OUT; i += blockDim.x) {
        sW0[i] = W2[i];
        sW1[i] = W2[H_HID * C_OUT + i];
    }
    if (threadIdx.x < C_OUT) sb[threadIdx.x] = b2[threadIdx.x];
    __syncthreads();
    int lane = threadIdx.x & 63;
    int wid  = threadIdx.x >> 6;
    int node = blockIdx.x * 8 + wid;
    int slot = lane >> 4, f = lane & 15;
    int beg = rowptr[node], end = rowptr[node + 1];
    float acc = 0.f;
    int j = beg + slot;
    while (j + 4 < end) {
        int s0 = col[j], s1 = col[j + 4];
        acc += sh[s0 * H_HID + f];
        acc += sh[s1 * H_HID + f];
        j += 8;
    }
    if (j < end) acc += sh[col[j] * H_HID + f];
    acc += __shfl_xor(acc, 16);
    acc += __shfl_xor(acc, 32);
    float t1   = -dinv[node] * acc;           // lane holds feature f
    float hval = h[node * H_HID + f];         // lane holds feature f
    int c = lane;                             // lane c computes class c (c<40)
    float o = (c < C_OUT) ? sb[c] : -1e30f;
    #pragma unroll
    for (int ff = 0; ff < H_HID; ++ff) {
        float hh = __shfl(hval, ff);          // slot-0 copy of feature ff
        float tt = __shfl(t1, ff);
        if (c < C_OUT) o += hh * sW0[ff * C_OUT + c] + tt * sW1[ff * C_OUT + c];
    }
    float mx = o;
    #pragma unroll
    for (int d = 1; d < 64; d <<= 1) mx = fmaxf(mx, __shfl_xor(mx, d));
    float ex = (c < C_OUT) ? expf(o - mx) : 0.f;
    float sum = ex;
    #pragma unroll
    for (int d = 1; d < 64; d <<= 1) sum += __shfl_xor(sum, d);
    float lse = mx + logf(sum);
    if (c < C_OUT) out[(size_t)node * C_OUT + c] = o - lse;
}

extern "C" void kernel_launch(void* const* d_in, const int* in_sizes, int n_in,
                              void* d_out, int out_size, void* d_ws, size_t ws_size,
                              hipStream_t stream) {
    const float* x   = (const float*)d_in[0];
    const int*   ei  = (const int*)d_in[1];
    const float* W1  = (const float*)d_in[2];
    const float* b1  = (const float*)d_in[3];
    const float* W2  = (const float*)d_in[4];
    const float* b2  = (const float*)d_in[5];
    float* out = (float*)d_out;

    const int* src = ei;            // edge_index[0]
    const int* dst = ei + N_EDGES;  // edge_index[1]

    // workspace layout
    int* partS = (int*)d_ws;                                      // NBLK*NBUCKP
    int* partD = partS + NBLK * NBUCKP;                           // NBLK*NBUCKP
    int* baseS = partD + NBLK * NBUCKP;                           // NBUCK+1 (pad 512)
    int* baseD = baseS + 512;                                     // NBUCK+1 (pad 512)
    unsigned int*  packedD = (unsigned int*)(baseD + 512);        // E
    unsigned char* srcloc  = (unsigned char*)(packedD + N_EDGES); // E bytes
    int*   col    = (int*)(srcloc + N_EDGES);                     // E
    int*   rowptr = col + N_EDGES;                                // N+1 (pad)
    float* dinv   = (float*)(rowptr + N_NODES + 8);               // N
    float* xw0    = dinv + N_NODES;                               // N*16
    float* sxw1   = xw0  + (size_t)N_NODES * H_HID;               // N*16
    float* h      = sxw1 + (size_t)N_NODES * H_HID;               // N*16
    float* sh     = h    + (size_t)N_NODES * H_HID;               // N*16

    bucket_count  <<<NBLK, 256, 0, stream>>>(src, dst, partS, partD);
    bucket_base   <<<2, 512, 0, stream>>>(partS, partD, baseS, baseD);
    bucket_scatter<<<NBLK, 512, 0, stream>>>(src, dst, partS, partD, baseS, baseD, packedD, srcloc);
    csr_build     <<<NBUCK, 256, 0, stream>>>(packedD, baseD, srcloc, baseS, col, rowptr, dinv);
    xw_kernel     <<<N_NODES / 16, 256, 0, stream>>>(x, W1, dinv, xw0, sxw1);
    gather1       <<<N_NODES / 8, 512, 0, stream>>>(rowptr, col, dinv, sxw1, xw0, b1, h, sh);
    gather2_out   <<<N_NODES / 8, 512, 0, stream>>>(rowptr, col, dinv, sh, h, W2, b2, out);
}

// Round 7
// 134.617 us; speedup vs baseline: 2.3492x; 1.1820x over previous
//
#include <hip/hip_runtime.h>
#include <math.h>

#define N_NODES 50000
#define N_EDGES 800000
#define D_IN    64
#define H_HID   16
#define C_OUT   40

#define BSH     7                                  // 128 nodes per bucket
#define BNODES  128
#define BMASK   127
#define NBUCK   ((N_NODES + BNODES - 1) / BNODES)  // 391
#define NBUCKP  400                                // padded stride for part arrays
#define NBLK    500                                // edge slabs
#define EPB     (N_EDGES / NBLK)                   // 1600 exact, 16B-aligned
#define EPB4    (EPB / 4)                          // 400 int4s per slab

// ---- pass A: per-(block,bucket) histograms, LDS only; part[block][bucket] ----
__global__ void bucket_count(const int* __restrict__ src, const int* __restrict__ dst,
                             int* __restrict__ partS, int* __restrict__ partD) {
    __shared__ int hS[NBUCK], hD[NBUCK];
    for (int i = threadIdx.x; i < NBUCK; i += blockDim.x) { hS[i] = 0; hD[i] = 0; }
    __syncthreads();
    const int4* s4 = (const int4*)(src + blockIdx.x * EPB);
    const int4* d4 = (const int4*)(dst + blockIdx.x * EPB);
    for (int k = threadIdx.x; k < EPB4; k += blockDim.x) {
        int4 s = s4[k], d = d4[k];
        atomicAdd(&hS[s.x >> BSH], 1); atomicAdd(&hS[s.y >> BSH], 1);
        atomicAdd(&hS[s.z >> BSH], 1); atomicAdd(&hS[s.w >> BSH], 1);
        atomicAdd(&hD[d.x >> BSH], 1); atomicAdd(&hD[d.y >> BSH], 1);
        atomicAdd(&hD[d.z >> BSH], 1); atomicAdd(&hD[d.w >> BSH], 1);
    }
    __syncthreads();
    for (int i = threadIdx.x; i < NBUCK; i += blockDim.x) {
        partS[blockIdx.x * NBUCKP + i] = hS[i];
        partD[blockIdx.x * NBUCKP + i] = hD[i];
    }
}

// ---- in-place prefix over blocks per bucket + bucket base offsets ----
// After this: part[k][b] = sum_{k'<k} count[k'][b]  (block-local base within bucket)
//             base[b]    = global start of bucket b
__global__ void bucket_base(int* __restrict__ partS, int* __restrict__ partD,
                            int* __restrict__ baseS, int* __restrict__ baseD) {
    int* part = blockIdx.x ? partD : partS;
    int* base = blockIdx.x ? baseD : baseS;
    __shared__ int tot[NBUCK];
    int b = threadIdx.x;
    if (b < NBUCK) {
        int acc = 0;
        for (int k = 0; k < NBLK; ++k) {        // coalesced across b
            int idx = k * NBUCKP + b;
            int v = part[idx];
            part[idx] = acc;
            acc += v;
        }
        tot[b] = acc;
    }
    __syncthreads();
    if (threadIdx.x == 0) {
        int acc = 0;
        for (int i = 0; i < NBUCK; ++i) { base[i] = acc; acc += tot[i]; }
        base[NBUCK] = acc;   // == N_EDGES
    }
}

// ---- pass B: scatter edges into bucket-grouped arrays; cursors = 2 coalesced loads ----
__global__ void bucket_scatter(const int* __restrict__ src, const int* __restrict__ dst,
                               const int* __restrict__ partS, const int* __restrict__ partD,
                               const int* __restrict__ baseS, const int* __restrict__ baseD,
                               unsigned int* __restrict__ packedD,
                               unsigned char* __restrict__ srcloc) {
    __shared__ int cS[NBUCK], cD[NBUCK];
    int blk = blockIdx.x;
    for (int b = threadIdx.x; b < NBUCK; b += blockDim.x) {
        cS[b] = baseS[b] + partS[blk * NBUCKP + b];
        cD[b] = baseD[b] + partD[blk * NBUCKP + b];
    }
    __syncthreads();
    const int4* s4 = (const int4*)(src + blk * EPB);
    const int4* d4 = (const int4*)(dst + blk * EPB);
    for (int k = threadIdx.x; k < EPB4; k += blockDim.x) {
        int4 sv = s4[k], dv = d4[k];
        int ss[4] = { sv.x, sv.y, sv.z, sv.w };
        int dd[4] = { dv.x, dv.y, dv.z, dv.w };
        #pragma unroll
        for (int u = 0; u < 4; ++u) {
            int s = ss[u], d = dd[u];
            int pD = atomicAdd(&cD[d >> BSH], 1);
            packedD[pD] = (unsigned)s | ((unsigned)(d & BMASK) << 16);
            int pS = atomicAdd(&cS[s >> BSH], 1);
            srcloc[pS] = (unsigned char)(s & BMASK);
        }
    }
}

// ---- per-bucket counting sort -> per-node CSR (col, rowptr) + src-degree -> dinv ----
__global__ void csr_build(const unsigned int* __restrict__ packedD, const int* __restrict__ baseD,
                          const unsigned char* __restrict__ srcloc, const int* __restrict__ baseS,
                          int* __restrict__ col, int* __restrict__ rowptr,
                          float* __restrict__ dinv) {
    __shared__ int hist[BNODES], scanv[BNODES], cur[BNODES], shist[BNODES];
    int tid = threadIdx.x;
    if (tid < BNODES) { hist[tid] = 0; shist[tid] = 0; }
    __syncthreads();
    int bb = blockIdx.x;
    int begD = baseD[bb], endD = baseD[bb + 1];
    for (int j = begD + tid; j < endD; j += blockDim.x)
        atomicAdd(&hist[(packedD[j] >> 16) & BMASK], 1);
    int begS = baseS[bb], endS = baseS[bb + 1];
    for (int j = begS + tid; j < endS; j += blockDim.x)
        atomicAdd(&shist[srcloc[j]], 1);
    __syncthreads();
    if (tid == 0) {
        int acc = 0;
        for (int i = 0; i < BNODES; ++i) { scanv[i] = acc; acc += hist[i]; }
    }
    __syncthreads();
    if (tid < BNODES) {
        cur[tid] = scanv[tid];
        int node = bb * BNODES + tid;
        if (node < N_NODES) {
            rowptr[node] = begD + scanv[tid];
            int d = shist[tid];
            dinv[node] = (d > 0) ? rsqrtf((float)d) : 0.0f;
        }
    }
    if (bb == NBUCK - 1 && tid == 0) rowptr[N_NODES] = endD;   // == N_EDGES
    __syncthreads();
    for (int j = begD + tid; j < endD; j += blockDim.x) {
        unsigned rec = packedD[j];
        int dl = (rec >> 16) & BMASK;
        int pos = atomicAdd(&cur[dl], 1);
        col[begD + pos] = (int)(rec & 0xFFFF);   // global src id (fits 16b: N<65536)
    }
}

// ---- xw0 = x@W1[0]; sxw1 = dinv * (x@W1[1]) ----
__global__ void xw_kernel(const float* __restrict__ x, const float* __restrict__ W1,
                          const float* __restrict__ dinv,
                          float* __restrict__ xw0, float* __restrict__ sxw1) {
    __shared__ float sW[2 * D_IN * H_HID];   // 8 KB
    __shared__ float sx[16 * 65];
    for (int i = threadIdx.x; i < 2 * D_IN * H_HID; i += 256) sW[i] = W1[i];
    int nbase = blockIdx.x * 16;
    for (int i = threadIdx.x; i < 16 * D_IN; i += 256) {
        int r = i >> 6, c = i & 63;
        sx[r * 65 + c] = x[(size_t)(nbase + r) * D_IN + c];
    }
    __syncthreads();
    int nl = threadIdx.x >> 4, f = threadIdx.x & 15;
    int node = nbase + nl;                    // N = 3125*16 exactly
    float a0 = 0.f, a1 = 0.f;
    #pragma unroll
    for (int d = 0; d < D_IN; ++d) {
        float xv = sx[nl * 65 + d];
        a0 += xv * sW[d * H_HID + f];
        a1 += xv * sW[D_IN * H_HID + d * H_HID + f];
    }
    int t = node * H_HID + f;
    xw0[t]  = a0;
    sxw1[t] = dinv[node] * a1;
}

// ---- layer-1 gather: one wave per node; 4 edge-slots x 16 feats; no atomics ----
__global__ void gather1(const int* __restrict__ rowptr, const int* __restrict__ col,
                        const float* __restrict__ dinv, const float* __restrict__ sxw1,
                        const float* __restrict__ xw0, const float* __restrict__ b1,
                        float* __restrict__ h, float* __restrict__ sh) {
    int lane = threadIdx.x & 63;
    int wid  = threadIdx.x >> 6;
    int node = blockIdx.x * 8 + wid;          // 6250*8 = 50000 exact
    int slot = lane >> 4, f = lane & 15;
    int beg = rowptr[node], end = rowptr[node + 1];
    float acc = 0.f;
    int j = beg + slot;
    while (j + 4 < end) {                     // 2-deep: 8 gathers in flight per wave
        int s0 = col[j], s1 = col[j + 4];
        acc += sxw1[s0 * H_HID + f];
        acc += sxw1[s1 * H_HID + f];
        j += 8;
    }
    if (j < end) acc += sxw1[col[j] * H_HID + f];
    acc += __shfl_xor(acc, 16);
    acc += __shfl_xor(acc, 32);
    if (slot == 0) {
        float di = dinv[node];
        float v = xw0[node * H_HID + f] - di * acc + b1[f];
        v = fmaxf(v, 0.f);
        h[node * H_HID + f]  = v;
        sh[node * H_HID + f] = di * v;
    }
}

// ---- layer-2 gather + dual matmul + log_softmax: one wave per node ----
__global__ void gather2_out(const int* __restrict__ rowptr, const int* __restrict__ col,
                            const float* __restrict__ dinv, const float* __restrict__ sh,
                            const float* __restrict__ h, const float* __restrict__ W2,
                            const float* __restrict__ b2, float* __restrict__ out) {
    __shared__ float sW0[H_HID * C_OUT], sW1[H_HID * C_OUT], sb[C_OUT];
    for (int i = threadIdx.x; i < H_HID * C_OUT; i += blockDim.x) {
        sW0[i] = W2[i];
        sW1[i] = W2[H_HID * C_OUT + i];
    }
    if (threadIdx.x < C_OUT) sb[threadIdx.x] = b2[threadIdx.x];
    __syncthreads();
    int lane = threadIdx.x & 63;
    int wid  = threadIdx.x >> 6;
    int node = blockIdx.x * 8 + wid;
    int slot = lane >> 4, f = lane & 15;
    int beg = rowptr[node], end = rowptr[node + 1];
    float acc = 0.f;
    int j = beg + slot;
    while (j + 4 < end) {
        int s0 = col[j], s1 = col[j + 4];
        acc += sh[s0 * H_HID + f];
        acc += sh[s1 * H_HID + f];
        j += 8;
    }
    if (j < end) acc += sh[col[j] * H_HID + f];
    acc += __shfl_xor(acc, 16);
    acc += __shfl_xor(acc, 32);
    float t1   = -dinv[node] * acc;           // lane holds feature f
    float hval = h[node * H_HID + f];         // lane holds feature f
    int c = lane;                             // lane c computes class c (c<40)
    float o = (c < C_OUT) ? sb[c] : -1e30f;
    #pragma unroll
    for (int ff = 0; ff < H_HID; ++ff) {
        float hh = __shfl(hval, ff);          // slot-0 copy of feature ff
        float tt = __shfl(t1, ff);
        if (c < C_OUT) o += hh * sW0[ff * C_OUT + c] + tt * sW1[ff * C_OUT + c];
    }
    float mx = o;
    #pragma unroll
    for (int d = 1; d < 64; d <<= 1) mx = fmaxf(mx, __shfl_xor(mx, d));
    float ex = (c < C_OUT) ? expf(o - mx) : 0.f;
    float sum = ex;
    #pragma unroll
    for (int d = 1; d < 64; d <<= 1) sum += __shfl_xor(sum, d);
    float lse = mx + logf(sum);
    if (c < C_OUT) out[(size_t)node * C_OUT + c] = o - lse;
}

extern "C" void kernel_launch(void* const* d_in, const int* in_sizes, int n_in,
                              void* d_out, int out_size, void* d_ws, size_t ws_size,
                              hipStream_t stream) {
    const float* x   = (const float*)d_in[0];
    const int*   ei  = (const int*)d_in[1];
    const float* W1  = (const float*)d_in[2];
    const float* b1  = (const float*)d_in[3];
    const float* W2  = (const float*)d_in[4];
    const float* b2  = (const float*)d_in[5];
    float* out = (float*)d_out;

    const int* src = ei;            // edge_index[0]
    const int* dst = ei + N_EDGES;  // edge_index[1]

    // workspace layout
    int* partS = (int*)d_ws;                                      // NBLK*NBUCKP
    int* partD = partS + NBLK * NBUCKP;                           // NBLK*NBUCKP
    int* baseS = partD + NBLK * NBUCKP;                           // NBUCK+1 (pad 512)
    int* baseD = baseS + 512;                                     // NBUCK+1 (pad 512)
    unsigned int*  packedD = (unsigned int*)(baseD + 512);        // E
    unsigned char* srcloc  = (unsigned char*)(packedD + N_EDGES); // E bytes
    int*   col    = (int*)(srcloc + N_EDGES);                     // E
    int*   rowptr = col + N_EDGES;                                // N+1 (pad)
    float* dinv   = (float*)(rowptr + N_NODES + 8);               // N
    float* xw0    = dinv + N_NODES;                               // N*16
    float* sxw1   = xw0  + (size_t)N_NODES * H_HID;               // N*16
    float* h      = sxw1 + (size_t)N_NODES * H_HID;               // N*16
    float* sh     = h    + (size_t)N_NODES * H_HID;               // N*16

    bucket_count  <<<NBLK, 256, 0, stream>>>(src, dst, partS, partD);
    bucket_base   <<<2, 512, 0, stream>>>(partS, partD, baseS, baseD);
    bucket_scatter<<<NBLK, 256, 0, stream>>>(src, dst, partS, partD, baseS, baseD, packedD, srcloc);
    csr_build     <<<NBUCK, 256, 0, stream>>>(packedD, baseD, srcloc, baseS, col, rowptr, dinv);
    xw_kernel     <<<N_NODES / 16, 256, 0, stream>>>(x, W1, dinv, xw0, sxw1);
    gather1       <<<N_NODES / 8, 512, 0, stream>>>(rowptr, col, dinv, sxw1, xw0, b1, h, sh);
    gather2_out   <<<N_NODES / 8, 512, 0, stream>>>(rowptr, col, dinv, sh, h, W2, b2, out);
}

// Round 8
// 117.582 us; speedup vs baseline: 2.6896x; 1.1449x over previous
//
#include <hip/hip_runtime.h>
#include <math.h>

#define N_NODES 50000
#define N_EDGES 800000
#define D_IN    64
#define H_HID   16
#define C_OUT   40

#define BSH     7                                  // 128 nodes per bucket
#define BNODES  128
#define BMASK   127
#define NBUCK   ((N_NODES + BNODES - 1) / BNODES)  // 391
#define NBUCKP  400                                // padded stride for part arrays
#define NBLK    500                                // edge slabs
#define EPB     (N_EDGES / NBLK)                   // 1600 exact, 16B-aligned
#define EPB4    (EPB / 4)                          // 400 int4s per slab

// ---- pass A: per-(block,bucket) histograms, LDS only; part[block][bucket] ----
__global__ void bucket_count(const int* __restrict__ src, const int* __restrict__ dst,
                             int* __restrict__ partS, int* __restrict__ partD) {
    __shared__ int hS[NBUCK], hD[NBUCK];
    for (int i = threadIdx.x; i < NBUCK; i += blockDim.x) { hS[i] = 0; hD[i] = 0; }
    __syncthreads();
    const int4* s4 = (const int4*)(src + blockIdx.x * EPB);
    const int4* d4 = (const int4*)(dst + blockIdx.x * EPB);
    for (int k = threadIdx.x; k < EPB4; k += blockDim.x) {
        int4 s = s4[k], d = d4[k];
        atomicAdd(&hS[s.x >> BSH], 1); atomicAdd(&hS[s.y >> BSH], 1);
        atomicAdd(&hS[s.z >> BSH], 1); atomicAdd(&hS[s.w >> BSH], 1);
        atomicAdd(&hD[d.x >> BSH], 1); atomicAdd(&hD[d.y >> BSH], 1);
        atomicAdd(&hD[d.z >> BSH], 1); atomicAdd(&hD[d.w >> BSH], 1);
    }
    __syncthreads();
    for (int i = threadIdx.x; i < NBUCK; i += blockDim.x) {
        partS[blockIdx.x * NBUCKP + i] = hS[i];
        partD[blockIdx.x * NBUCKP + i] = hD[i];
    }
}

// ---- in-place prefix over blocks per bucket + bucket base offsets ----
__global__ void bucket_base(int* __restrict__ partS, int* __restrict__ partD,
                            int* __restrict__ baseS, int* __restrict__ baseD) {
    int* part = blockIdx.x ? partD : partS;
    int* base = blockIdx.x ? baseD : baseS;
    __shared__ int tot[NBUCK];
    int b = threadIdx.x;
    if (b < NBUCK) {
        int acc = 0;
        for (int k = 0; k < NBLK; ++k) {        // coalesced across b
            int idx = k * NBUCKP + b;
            int v = part[idx];
            part[idx] = acc;
            acc += v;
        }
        tot[b] = acc;
    }
    __syncthreads();
    if (threadIdx.x == 0) {
        int acc = 0;
        for (int i = 0; i < NBUCK; ++i) { base[i] = acc; acc += tot[i]; }
        base[NBUCK] = acc;   // == N_EDGES
    }
}

// ---- pass B: scatter edges into bucket-grouped arrays; cursors = 2 coalesced loads ----
__global__ void bucket_scatter(const int* __restrict__ src, const int* __restrict__ dst,
                               const int* __restrict__ partS, const int* __restrict__ partD,
                               const int* __restrict__ baseS, const int* __restrict__ baseD,
                               unsigned int* __restrict__ packedD,
                               unsigned char* __restrict__ srcloc) {
    __shared__ int cS[NBUCK], cD[NBUCK];
    int blk = blockIdx.x;
    for (int b = threadIdx.x; b < NBUCK; b += blockDim.x) {
        cS[b] = baseS[b] + partS[blk * NBUCKP + b];
        cD[b] = baseD[b] + partD[blk * NBUCKP + b];
    }
    __syncthreads();
    const int4* s4 = (const int4*)(src + blk * EPB);
    const int4* d4 = (const int4*)(dst + blk * EPB);
    for (int k = threadIdx.x; k < EPB4; k += blockDim.x) {
        int4 sv = s4[k], dv = d4[k];
        int ss[4] = { sv.x, sv.y, sv.z, sv.w };
        int dd[4] = { dv.x, dv.y, dv.z, dv.w };
        #pragma unroll
        for (int u = 0; u < 4; ++u) {
            int s = ss[u], d = dd[u];
            int pD = atomicAdd(&cD[d >> BSH], 1);
            packedD[pD] = (unsigned)s | ((unsigned)(d & BMASK) << 16);
            int pS = atomicAdd(&cS[s >> BSH], 1);
            srcloc[pS] = (unsigned char)(s & BMASK);
        }
    }
}

// ---- per-bucket counting sort -> per-node CSR (col, rowptr) + src-degree -> dinv ----
__global__ void csr_build(const unsigned int* __restrict__ packedD, const int* __restrict__ baseD,
                          const unsigned char* __restrict__ srcloc, const int* __restrict__ baseS,
                          int* __restrict__ col, int* __restrict__ rowptr,
                          float* __restrict__ dinv) {
    __shared__ int hist[BNODES], scanv[BNODES], cur[BNODES], shist[BNODES];
    int tid = threadIdx.x;
    if (tid < BNODES) { hist[tid] = 0; shist[tid] = 0; }
    __syncthreads();
    int bb = blockIdx.x;
    int begD = baseD[bb], endD = baseD[bb + 1];
    for (int j = begD + tid; j < endD; j += blockDim.x)
        atomicAdd(&hist[(packedD[j] >> 16) & BMASK], 1);
    int begS = baseS[bb], endS = baseS[bb + 1];
    for (int j = begS + tid; j < endS; j += blockDim.x)
        atomicAdd(&shist[srcloc[j]], 1);
    __syncthreads();
    if (tid == 0) {
        int acc = 0;
        for (int i = 0; i < BNODES; ++i) { scanv[i] = acc; acc += hist[i]; }
    }
    __syncthreads();
    if (tid < BNODES) {
        cur[tid] = scanv[tid];
        int node = bb * BNODES + tid;
        if (node < N_NODES) {
            rowptr[node] = begD + scanv[tid];
            int d = shist[tid];
            dinv[node] = (d > 0) ? rsqrtf((float)d) : 0.0f;
        }
    }
    if (bb == NBUCK - 1 && tid == 0) rowptr[N_NODES] = endD;   // == N_EDGES
    __syncthreads();
    for (int j = begD + tid; j < endD; j += blockDim.x) {
        unsigned rec = packedD[j];
        int dl = (rec >> 16) & BMASK;
        int pos = atomicAdd(&cur[dl], 1);
        col[begD + pos] = (int)(rec & 0xFFFF);   // global src id (fits 16b: N<65536)
    }
}

// ---- xw0 = x@W1[0]; sxw1 = dinv * (x@W1[1]) ----
__global__ void xw_kernel(const float* __restrict__ x, const float* __restrict__ W1,
                          const float* __restrict__ dinv,
                          float* __restrict__ xw0, float* __restrict__ sxw1) {
    __shared__ float sW[2 * D_IN * H_HID];   // 8 KB
    __shared__ float sx[16 * 65];
    for (int i = threadIdx.x; i < 2 * D_IN * H_HID; i += 256) sW[i] = W1[i];
    int nbase = blockIdx.x * 16;
    for (int i = threadIdx.x; i < 16 * D_IN; i += 256) {
        int r = i >> 6, c = i & 63;
        sx[r * 65 + c] = x[(size_t)(nbase + r) * D_IN + c];
    }
    __syncthreads();
    int nl = threadIdx.x >> 4, f = threadIdx.x & 15;
    int node = nbase + nl;                    // N = 3125*16 exactly
    float a0 = 0.f, a1 = 0.f;
    #pragma unroll
    for (int d = 0; d < D_IN; ++d) {
        float xv = sx[nl * 65 + d];
        a0 += xv * sW[d * H_HID + f];
        a1 += xv * sW[D_IN * H_HID + d * H_HID + f];
    }
    int t = node * H_HID + f;
    xw0[t]  = a0;
    sxw1[t] = dinv[node] * a1;
}

// ---- layer-1 gather: 16 lanes per node, 4 nodes/wave, 8-deep unroll, no shuffles ----
__global__ void gather1(const int* __restrict__ rowptr, const int* __restrict__ col,
                        const float* __restrict__ dinv, const float* __restrict__ sxw1,
                        const float* __restrict__ xw0, const float* __restrict__ b1,
                        float* __restrict__ h, float* __restrict__ sh) {
    int grp = threadIdx.x >> 4;               // 32 groups per 512-thread block
    int f   = threadIdx.x & 15;
    int node = blockIdx.x * 32 + grp;
    if (node >= N_NODES) return;
    int beg = rowptr[node], end = rowptr[node + 1];
    float acc = 0.f;
    int j = beg;
    for (; j + 8 <= end; j += 8) {            // 8 cols -> 8 independent gathers in flight
        int c0 = col[j],     c1 = col[j + 1], c2 = col[j + 2], c3 = col[j + 3];
        int c4 = col[j + 4], c5 = col[j + 5], c6 = col[j + 6], c7 = col[j + 7];
        float v0 = sxw1[c0 * H_HID + f], v1 = sxw1[c1 * H_HID + f];
        float v2 = sxw1[c2 * H_HID + f], v3 = sxw1[c3 * H_HID + f];
        float v4 = sxw1[c4 * H_HID + f], v5 = sxw1[c5 * H_HID + f];
        float v6 = sxw1[c6 * H_HID + f], v7 = sxw1[c7 * H_HID + f];
        acc += ((v0 + v1) + (v2 + v3)) + ((v4 + v5) + (v6 + v7));
    }
    for (; j < end; ++j) acc += sxw1[col[j] * H_HID + f];
    float di = dinv[node];
    float v = xw0[node * H_HID + f] - di * acc + b1[f];
    v = fmaxf(v, 0.f);
    h[node * H_HID + f]  = v;
    sh[node * H_HID + f] = di * v;
}

// ---- layer-2 gather: t1 = -dinv * sum sh[neighbors]; same structure ----
__global__ void gather2(const int* __restrict__ rowptr, const int* __restrict__ col,
                        const float* __restrict__ dinv, const float* __restrict__ sh,
                        float* __restrict__ t1) {
    int grp = threadIdx.x >> 4;
    int f   = threadIdx.x & 15;
    int node = blockIdx.x * 32 + grp;
    if (node >= N_NODES) return;
    int beg = rowptr[node], end = rowptr[node + 1];
    float acc = 0.f;
    int j = beg;
    for (; j + 8 <= end; j += 8) {
        int c0 = col[j],     c1 = col[j + 1], c2 = col[j + 2], c3 = col[j + 3];
        int c4 = col[j + 4], c5 = col[j + 5], c6 = col[j + 6], c7 = col[j + 7];
        float v0 = sh[c0 * H_HID + f], v1 = sh[c1 * H_HID + f];
        float v2 = sh[c2 * H_HID + f], v3 = sh[c3 * H_HID + f];
        float v4 = sh[c4 * H_HID + f], v5 = sh[c5 * H_HID + f];
        float v6 = sh[c6 * H_HID + f], v7 = sh[c7 * H_HID + f];
        acc += ((v0 + v1) + (v2 + v3)) + ((v4 + v5) + (v6 + v7));
    }
    for (; j < end; ++j) acc += sh[col[j] * H_HID + f];
    t1[node * H_HID + f] = -dinv[node] * acc;
}

// ---- final: node-per-thread dual matmul + log_softmax, zero cross-lane ops ----
__global__ void out_kernel(const float* __restrict__ h, const float* __restrict__ t1,
                           const float* __restrict__ W2, const float* __restrict__ b2,
                           float* __restrict__ out) {
    __shared__ float sW0[H_HID * C_OUT], sW1[H_HID * C_OUT], sb[C_OUT];
    for (int i = threadIdx.x; i < H_HID * C_OUT; i += blockDim.x) {
        sW0[i] = W2[i];
        sW1[i] = W2[H_HID * C_OUT + i];
    }
    if (threadIdx.x < C_OUT) sb[threadIdx.x] = b2[threadIdx.x];
    __syncthreads();
    int node = blockIdx.x * blockDim.x + threadIdx.x;
    if (node >= N_NODES) return;
    float hv[H_HID], tv[H_HID];
    const float4* h4 = (const float4*)(h  + (size_t)node * H_HID);
    const float4* t4 = (const float4*)(t1 + (size_t)node * H_HID);
    #pragma unroll
    for (int q = 0; q < 4; ++q) {
        float4 a = h4[q], b = t4[q];
        hv[q*4+0] = a.x; hv[q*4+1] = a.y; hv[q*4+2] = a.z; hv[q*4+3] = a.w;
        tv[q*4+0] = b.x; tv[q*4+1] = b.y; tv[q*4+2] = b.z; tv[q*4+3] = b.w;
    }
    float o[C_OUT];
    float mx = -1e30f;
    #pragma unroll
    for (int c = 0; c < C_OUT; ++c) {
        float a = sb[c];
        #pragma unroll
        for (int ff = 0; ff < H_HID; ++ff)
            a += hv[ff] * sW0[ff * C_OUT + c] + tv[ff] * sW1[ff * C_OUT + c];
        o[c] = a;
        mx = fmaxf(mx, a);
    }
    float sum = 0.f;
    #pragma unroll
    for (int c = 0; c < C_OUT; ++c) sum += expf(o[c] - mx);
    float lse = mx + logf(sum);
    float* op = out + (size_t)node * C_OUT;
    #pragma unroll
    for (int q = 0; q < 10; ++q) {
        float4 w = make_float4(o[q*4+0] - lse, o[q*4+1] - lse, o[q*4+2] - lse, o[q*4+3] - lse);
        ((float4*)op)[q] = w;
    }
}

extern "C" void kernel_launch(void* const* d_in, const int* in_sizes, int n_in,
                              void* d_out, int out_size, void* d_ws, size_t ws_size,
                              hipStream_t stream) {
    const float* x   = (const float*)d_in[0];
    const int*   ei  = (const int*)d_in[1];
    const float* W1  = (const float*)d_in[2];
    const float* b1  = (const float*)d_in[3];
    const float* W2  = (const float*)d_in[4];
    const float* b2  = (const float*)d_in[5];
    float* out = (float*)d_out;

    const int* src = ei;            // edge_index[0]
    const int* dst = ei + N_EDGES;  // edge_index[1]

    // workspace layout
    int* partS = (int*)d_ws;                                      // NBLK*NBUCKP
    int* partD = partS + NBLK * NBUCKP;                           // NBLK*NBUCKP
    int* baseS = partD + NBLK * NBUCKP;                           // NBUCK+1 (pad 512)
    int* baseD = baseS + 512;                                     // NBUCK+1 (pad 512)
    unsigned int*  packedD = (unsigned int*)(baseD + 512);        // E
    unsigned char* srcloc  = (unsigned char*)(packedD + N_EDGES); // E bytes
    int*   col    = (int*)(srcloc + N_EDGES);                     // E
    int*   rowptr = col + N_EDGES;                                // N+1 (pad)
    float* dinv   = (float*)(rowptr + N_NODES + 8);               // N
    float* xw0    = dinv + N_NODES;                               // N*16
    float* sxw1   = xw0  + (size_t)N_NODES * H_HID;               // N*16
    float* h      = sxw1 + (size_t)N_NODES * H_HID;               // N*16
    float* sh     = h    + (size_t)N_NODES * H_HID;               // N*16
    float* t1     = sxw1;   // reuse: sxw1 dead after gather1 completes

    bucket_count  <<<NBLK, 256, 0, stream>>>(src, dst, partS, partD);
    bucket_base   <<<2, 512, 0, stream>>>(partS, partD, baseS, baseD);
    bucket_scatter<<<NBLK, 256, 0, stream>>>(src, dst, partS, partD, baseS, baseD, packedD, srcloc);
    csr_build     <<<NBUCK, 256, 0, stream>>>(packedD, baseD, srcloc, baseS, col, rowptr, dinv);
    xw_kernel     <<<N_NODES / 16, 256, 0, stream>>>(x, W1, dinv, xw0, sxw1);
    gather1       <<<(N_NODES + 31) / 32, 512, 0, stream>>>(rowptr, col, dinv, sxw1, xw0, b1, h, sh);
    gather2       <<<(N_NODES + 31) / 32, 512, 0, stream>>>(rowptr, col, dinv, sh, t1);
    out_kernel    <<<(N_NODES + 255) / 256, 256, 0, stream>>>(h, t1, W2, b2, out);
}

// Round 9
// 112.980 us; speedup vs baseline: 2.7991x; 1.0407x over previous
//
#include <hip/hip_runtime.h>
#include <math.h>

#define N_NODES 50000
#define N_EDGES 800000
#define D_IN    64
#define H_HID   16
#define C_OUT   40

#define BSH     7                                  // 128 nodes per bucket
#define BNODES  128
#define BMASK   127
#define NBUCK   ((N_NODES + BNODES - 1) / BNODES)  // 391
#define NBUCKP  400                                // padded stride for part arrays
#define NBLK    500                                // edge slabs
#define EPB     (N_EDGES / NBLK)                   // 1600 exact, 16B-aligned
#define EPB4    (EPB / 4)                          // 400 int4s per slab

// ---- pass A: per-(block,bucket) histograms, LDS only; part[block][bucket] ----
__global__ void bucket_count(const int* __restrict__ src, const int* __restrict__ dst,
                             int* __restrict__ partS, int* __restrict__ partD) {
    __shared__ int hS[NBUCK], hD[NBUCK];
    for (int i = threadIdx.x; i < NBUCK; i += blockDim.x) { hS[i] = 0; hD[i] = 0; }
    __syncthreads();
    const int4* s4 = (const int4*)(src + blockIdx.x * EPB);
    const int4* d4 = (const int4*)(dst + blockIdx.x * EPB);
    for (int k = threadIdx.x; k < EPB4; k += blockDim.x) {
        int4 s = s4[k], d = d4[k];
        atomicAdd(&hS[s.x >> BSH], 1); atomicAdd(&hS[s.y >> BSH], 1);
        atomicAdd(&hS[s.z >> BSH], 1); atomicAdd(&hS[s.w >> BSH], 1);
        atomicAdd(&hD[d.x >> BSH], 1); atomicAdd(&hD[d.y >> BSH], 1);
        atomicAdd(&hD[d.z >> BSH], 1); atomicAdd(&hD[d.w >> BSH], 1);
    }
    __syncthreads();
    for (int i = threadIdx.x; i < NBUCK; i += blockDim.x) {
        partS[blockIdx.x * NBUCKP + i] = hS[i];
        partD[blockIdx.x * NBUCKP + i] = hD[i];
    }
}

// ---- in-place prefix over blocks per bucket + bucket base offsets ----
__global__ void bucket_base(int* __restrict__ partS, int* __restrict__ partD,
                            int* __restrict__ baseS, int* __restrict__ baseD) {
    int* part = blockIdx.x ? partD : partS;
    int* base = blockIdx.x ? baseD : baseS;
    __shared__ int tot[NBUCK];
    int b = threadIdx.x;
    if (b < NBUCK) {
        int acc = 0;
        for (int k = 0; k < NBLK; ++k) {        // coalesced across b
            int idx = k * NBUCKP + b;
            int v = part[idx];
            part[idx] = acc;
            acc += v;
        }
        tot[b] = acc;
    }
    __syncthreads();
    if (threadIdx.x == 0) {
        int acc = 0;
        for (int i = 0; i < NBUCK; ++i) { base[i] = acc; acc += tot[i]; }
        base[NBUCK] = acc;   // == N_EDGES
    }
}

// ---- pass B: scatter edges into bucket-grouped arrays; cursors = 2 coalesced loads ----
__global__ void bucket_scatter(const int* __restrict__ src, const int* __restrict__ dst,
                               const int* __restrict__ partS, const int* __restrict__ partD,
                               const int* __restrict__ baseS, const int* __restrict__ baseD,
                               unsigned int* __restrict__ packedD,
                               unsigned char* __restrict__ srcloc) {
    __shared__ int cS[NBUCK], cD[NBUCK];
    int blk = blockIdx.x;
    for (int b = threadIdx.x; b < NBUCK; b += blockDim.x) {
        cS[b] = baseS[b] + partS[blk * NBUCKP + b];
        cD[b] = baseD[b] + partD[blk * NBUCKP + b];
    }
    __syncthreads();
    const int4* s4 = (const int4*)(src + blk * EPB);
    const int4* d4 = (const int4*)(dst + blk * EPB);
    for (int k = threadIdx.x; k < EPB4; k += blockDim.x) {
        int4 sv = s4[k], dv = d4[k];
        int ss[4] = { sv.x, sv.y, sv.z, sv.w };
        int dd[4] = { dv.x, dv.y, dv.z, dv.w };
        #pragma unroll
        for (int u = 0; u < 4; ++u) {
            int s = ss[u], d = dd[u];
            int pD = atomicAdd(&cD[d >> BSH], 1);
            packedD[pD] = (unsigned)s | ((unsigned)(d & BMASK) << 16);
            int pS = atomicAdd(&cS[s >> BSH], 1);
            srcloc[pS] = (unsigned char)(s & BMASK);
        }
    }
}

// ---- per-bucket counting sort -> per-node CSR (col, rowptr) + src-degree -> dinv ----
__global__ void csr_build(const unsigned int* __restrict__ packedD, const int* __restrict__ baseD,
                          const unsigned char* __restrict__ srcloc, const int* __restrict__ baseS,
                          int* __restrict__ col, int* __restrict__ rowptr,
                          float* __restrict__ dinv) {
    __shared__ int hist[BNODES], scanv[BNODES], cur[BNODES], shist[BNODES];
    int tid = threadIdx.x;
    if (tid < BNODES) { hist[tid] = 0; shist[tid] = 0; }
    __syncthreads();
    int bb = blockIdx.x;
    int begD = baseD[bb], endD = baseD[bb + 1];
    for (int j = begD + tid; j < endD; j += blockDim.x)
        atomicAdd(&hist[(packedD[j] >> 16) & BMASK], 1);
    int begS = baseS[bb], endS = baseS[bb + 1];
    for (int j = begS + tid; j < endS; j += blockDim.x)
        atomicAdd(&shist[srcloc[j]], 1);
    __syncthreads();
    if (tid == 0) {
        int acc = 0;
        for (int i = 0; i < BNODES; ++i) { scanv[i] = acc; acc += hist[i]; }
    }
    __syncthreads();
    if (tid < BNODES) {
        cur[tid] = scanv[tid];
        int node = bb * BNODES + tid;
        if (node < N_NODES) {
            rowptr[node] = begD + scanv[tid];
            int d = shist[tid];
            dinv[node] = (d > 0) ? rsqrtf((float)d) : 0.0f;
        }
    }
    if (bb == NBUCK - 1 && tid == 0) rowptr[N_NODES] = endD;   // == N_EDGES
    __syncthreads();
    for (int j = begD + tid; j < endD; j += blockDim.x) {
        unsigned rec = packedD[j];
        int dl = (rec >> 16) & BMASK;
        int pos = atomicAdd(&cur[dl], 1);
        col[begD + pos] = (int)(rec & 0xFFFF);   // global src id (fits 16b: N<65536)
    }
}

// ---- xw0 = x@W1[0]; sxw1 = dinv * (x@W1[1]) ----
__global__ void xw_kernel(const float* __restrict__ x, const float* __restrict__ W1,
                          const float* __restrict__ dinv,
                          float* __restrict__ xw0, float* __restrict__ sxw1) {
    __shared__ float sW[2 * D_IN * H_HID];   // 8 KB
    __shared__ float sx[16 * 65];
    for (int i = threadIdx.x; i < 2 * D_IN * H_HID; i += 256) sW[i] = W1[i];
    int nbase = blockIdx.x * 16;
    for (int i = threadIdx.x; i < 16 * D_IN; i += 256) {
        int r = i >> 6, c = i & 63;
        sx[r * 65 + c] = x[(size_t)(nbase + r) * D_IN + c];
    }
    __syncthreads();
    int nl = threadIdx.x >> 4, f = threadIdx.x & 15;
    int node = nbase + nl;                    // N = 3125*16 exactly
    float a0 = 0.f, a1 = 0.f;
    #pragma unroll
    for (int d = 0; d < D_IN; ++d) {
        float xv = sx[nl * 65 + d];
        a0 += xv * sW[d * H_HID + f];
        a1 += xv * sW[D_IN * H_HID + d * H_HID + f];
    }
    int t = node * H_HID + f;
    xw0[t]  = a0;
    sxw1[t] = dinv[node] * a1;
}

// ---- layer-1 gather: 8 lanes per node (float2/lane), 8 nodes/wave, 8-deep unroll ----
__global__ void gather1(const int* __restrict__ rowptr, const int* __restrict__ col,
                        const float* __restrict__ dinv, const float* __restrict__ sxw1,
                        const float* __restrict__ xw0, const float* __restrict__ b1,
                        float* __restrict__ h, float* __restrict__ sh) {
    int grp = threadIdx.x >> 3;               // 64 groups per 512-thread block
    int f2  = threadIdx.x & 7;                // feature pair index
    int node = blockIdx.x * 64 + grp;
    if (node >= N_NODES) return;
    int beg = rowptr[node], end = rowptr[node + 1];
    const float2* sx2 = (const float2*)sxw1;
    float ax = 0.f, ay = 0.f;
    int j = beg;
    for (; j + 8 <= end; j += 8) {            // 8 independent 8B gathers in flight
        int c0 = col[j],     c1 = col[j + 1], c2 = col[j + 2], c3 = col[j + 3];
        int c4 = col[j + 4], c5 = col[j + 5], c6 = col[j + 6], c7 = col[j + 7];
        float2 v0 = sx2[c0 * 8 + f2], v1 = sx2[c1 * 8 + f2];
        float2 v2 = sx2[c2 * 8 + f2], v3 = sx2[c3 * 8 + f2];
        float2 v4 = sx2[c4 * 8 + f2], v5 = sx2[c5 * 8 + f2];
        float2 v6 = sx2[c6 * 8 + f2], v7 = sx2[c7 * 8 + f2];
        ax += ((v0.x + v1.x) + (v2.x + v3.x)) + ((v4.x + v5.x) + (v6.x + v7.x));
        ay += ((v0.y + v1.y) + (v2.y + v3.y)) + ((v4.y + v5.y) + (v6.y + v7.y));
    }
    for (; j < end; ++j) {
        float2 v = sx2[col[j] * 8 + f2];
        ax += v.x; ay += v.y;
    }
    float di = dinv[node];
    float2 x0 = ((const float2*)xw0)[node * 8 + f2];
    float2 bb = ((const float2*)b1)[f2];
    float vx = fmaxf(x0.x - di * ax + bb.x, 0.f);
    float vy = fmaxf(x0.y - di * ay + bb.y, 0.f);
    ((float2*)h)[node * 8 + f2]  = make_float2(vx, vy);
    ((float2*)sh)[node * 8 + f2] = make_float2(di * vx, di * vy);
}

// ---- layer-2 gather: t1 = -dinv * sum sh[neighbors]; same structure ----
__global__ void gather2(const int* __restrict__ rowptr, const int* __restrict__ col,
                        const float* __restrict__ dinv, const float* __restrict__ sh,
                        float* __restrict__ t1) {
    int grp = threadIdx.x >> 3;
    int f2  = threadIdx.x & 7;
    int node = blockIdx.x * 64 + grp;
    if (node >= N_NODES) return;
    int beg = rowptr[node], end = rowptr[node + 1];
    const float2* sh2 = (const float2*)sh;
    float ax = 0.f, ay = 0.f;
    int j = beg;
    for (; j + 8 <= end; j += 8) {
        int c0 = col[j],     c1 = col[j + 1], c2 = col[j + 2], c3 = col[j + 3];
        int c4 = col[j + 4], c5 = col[j + 5], c6 = col[j + 6], c7 = col[j + 7];
        float2 v0 = sh2[c0 * 8 + f2], v1 = sh2[c1 * 8 + f2];
        float2 v2 = sh2[c2 * 8 + f2], v3 = sh2[c3 * 8 + f2];
        float2 v4 = sh2[c4 * 8 + f2], v5 = sh2[c5 * 8 + f2];
        float2 v6 = sh2[c6 * 8 + f2], v7 = sh2[c7 * 8 + f2];
        ax += ((v0.x + v1.x) + (v2.x + v3.x)) + ((v4.x + v5.x) + (v6.x + v7.x));
        ay += ((v0.y + v1.y) + (v2.y + v3.y)) + ((v4.y + v5.y) + (v6.y + v7.y));
    }
    for (; j < end; ++j) {
        float2 v = sh2[col[j] * 8 + f2];
        ax += v.x; ay += v.y;
    }
    float di = dinv[node];
    ((float2*)t1)[node * 8 + f2] = make_float2(-di * ax, -di * ay);
}

// ---- final: node-per-thread dual matmul + log_softmax, zero cross-lane ops ----
__global__ void out_kernel(const float* __restrict__ h, const float* __restrict__ t1,
                           const float* __restrict__ W2, const float* __restrict__ b2,
                           float* __restrict__ out) {
    __shared__ float sW0[H_HID * C_OUT], sW1[H_HID * C_OUT], sb[C_OUT];
    for (int i = threadIdx.x; i < H_HID * C_OUT; i += blockDim.x) {
        sW0[i] = W2[i];
        sW1[i] = W2[H_HID * C_OUT + i];
    }
    if (threadIdx.x < C_OUT) sb[threadIdx.x] = b2[threadIdx.x];
    __syncthreads();
    int node = blockIdx.x * blockDim.x + threadIdx.x;
    if (node >= N_NODES) return;
    float hv[H_HID], tv[H_HID];
    const float4* h4 = (const float4*)(h  + (size_t)node * H_HID);
    const float4* t4 = (const float4*)(t1 + (size_t)node * H_HID);
    #pragma unroll
    for (int q = 0; q < 4; ++q) {
        float4 a = h4[q], b = t4[q];
        hv[q*4+0] = a.x; hv[q*4+1] = a.y; hv[q*4+2] = a.z; hv[q*4+3] = a.w;
        tv[q*4+0] = b.x; tv[q*4+1] = b.y; tv[q*4+2] = b.z; tv[q*4+3] = b.w;
    }
    float o[C_OUT];
    float mx = -1e30f;
    #pragma unroll
    for (int c = 0; c < C_OUT; ++c) {
        float a = sb[c];
        #pragma unroll
        for (int ff = 0; ff < H_HID; ++ff)
            a += hv[ff] * sW0[ff * C_OUT + c] + tv[ff] * sW1[ff * C_OUT + c];
        o[c] = a;
        mx = fmaxf(mx, a);
    }
    float sum = 0.f;
    #pragma unroll
    for (int c = 0; c < C_OUT; ++c) sum += expf(o[c] - mx);
    float lse = mx + logf(sum);
    float* op = out + (size_t)node * C_OUT;
    #pragma unroll
    for (int q = 0; q < 10; ++q) {
        float4 w = make_float4(o[q*4+0] - lse, o[q*4+1] - lse, o[q*4+2] - lse, o[q*4+3] - lse);
        ((float4*)op)[q] = w;
    }
}

extern "C" void kernel_launch(void* const* d_in, const int* in_sizes, int n_in,
                              void* d_out, int out_size, void* d_ws, size_t ws_size,
                              hipStream_t stream) {
    const float* x   = (const float*)d_in[0];
    const int*   ei  = (const int*)d_in[1];
    const float* W1  = (const float*)d_in[2];
    const float* b1  = (const float*)d_in[3];
    const float* W2  = (const float*)d_in[4];
    const float* b2  = (const float*)d_in[5];
    float* out = (float*)d_out;

    const int* src = ei;            // edge_index[0]
    const int* dst = ei + N_EDGES;  // edge_index[1]

    // workspace layout
    int* partS = (int*)d_ws;                                      // NBLK*NBUCKP
    int* partD = partS + NBLK * NBUCKP;                           // NBLK*NBUCKP
    int* baseS = partD + NBLK * NBUCKP;                           // NBUCK+1 (pad 512)
    int* baseD = baseS + 512;                                     // NBUCK+1 (pad 512)
    unsigned int*  packedD = (unsigned int*)(baseD + 512);        // E
    unsigned char* srcloc  = (unsigned char*)(packedD + N_EDGES); // E bytes
    int*   col    = (int*)(srcloc + N_EDGES);                     // E
    int*   rowptr = col + N_EDGES;                                // N+1 (pad)
    float* dinv   = (float*)(rowptr + N_NODES + 8);               // N
    float* xw0    = dinv + N_NODES;                               // N*16
    float* sxw1   = xw0  + (size_t)N_NODES * H_HID;               // N*16
    float* h      = sxw1 + (size_t)N_NODES * H_HID;               // N*16
    float* sh     = h    + (size_t)N_NODES * H_HID;               // N*16
    float* t1     = sxw1;   // reuse: sxw1 dead after gather1 completes

    bucket_count  <<<NBLK, 256, 0, stream>>>(src, dst, partS, partD);
    bucket_base   <<<2, 512, 0, stream>>>(partS, partD, baseS, baseD);
    bucket_scatter<<<NBLK, 256, 0, stream>>>(src, dst, partS, partD, baseS, baseD, packedD, srcloc);
    csr_build     <<<NBUCK, 512, 0, stream>>>(packedD, baseD, srcloc, baseS, col, rowptr, dinv);
    xw_kernel     <<<N_NODES / 16, 256, 0, stream>>>(x, W1, dinv, xw0, sxw1);
    gather1       <<<(N_NODES + 63) / 64, 512, 0, stream>>>(rowptr, col, dinv, sxw1, xw0, b1, h, sh);
    gather2       <<<(N_NODES + 63) / 64, 512, 0, stream>>>(rowptr, col, dinv, sh, t1);
    out_kernel    <<<(N_NODES + 255) / 256, 256, 0, stream>>>(h, t1, W2, b2, out);
}

// Round 10
// 95.294 us; speedup vs baseline: 3.3186x; 1.1856x over previous
//
#include <hip/hip_runtime.h>
#include <math.h>

#define N_NODES 50000
#define N_EDGES 800000
#define D_IN    64
#define H_HID   16
#define C_OUT   40

#define BSH     7                                  // 128 nodes per bucket
#define BNODES  128
#define BMASK   127
#define NBUCK   ((N_NODES + BNODES - 1) / BNODES)  // 391
#define NBUCKP  400                                // padded stride for part arrays
#define NBLK    500                                // edge slabs
#define EPB     (N_EDGES / NBLK)                   // 1600 exact, 16B-aligned
#define EPB4    (EPB / 4)                          // 400 int4s per slab

// ---- pass A: per-(block,bucket) histograms, LDS only; part[block][bucket] ----
__global__ void bucket_count(const int* __restrict__ src, const int* __restrict__ dst,
                             int* __restrict__ partS, int* __restrict__ partD) {
    __shared__ int hS[NBUCK], hD[NBUCK];
    for (int i = threadIdx.x; i < NBUCK; i += blockDim.x) { hS[i] = 0; hD[i] = 0; }
    __syncthreads();
    const int4* s4 = (const int4*)(src + blockIdx.x * EPB);
    const int4* d4 = (const int4*)(dst + blockIdx.x * EPB);
    for (int k = threadIdx.x; k < EPB4; k += blockDim.x) {
        int4 s = s4[k], d = d4[k];
        atomicAdd(&hS[s.x >> BSH], 1); atomicAdd(&hS[s.y >> BSH], 1);
        atomicAdd(&hS[s.z >> BSH], 1); atomicAdd(&hS[s.w >> BSH], 1);
        atomicAdd(&hD[d.x >> BSH], 1); atomicAdd(&hD[d.y >> BSH], 1);
        atomicAdd(&hD[d.z >> BSH], 1); atomicAdd(&hD[d.w >> BSH], 1);
    }
    __syncthreads();
    for (int i = threadIdx.x; i < NBUCK; i += blockDim.x) {
        partS[blockIdx.x * NBUCKP + i] = hS[i];
        partD[blockIdx.x * NBUCKP + i] = hD[i];
    }
}

// ---- prefix over blocks, one block per (bucket, S/D): part[k][b] <- sum_{k'<k} ----
__global__ void bucket_base_scan(int* __restrict__ partS, int* __restrict__ partD,
                                 int* __restrict__ totS, int* __restrict__ totD) {
    int* part = blockIdx.y ? partD : partS;
    int* tot  = blockIdx.y ? totD  : totS;
    int b = blockIdx.x;
    __shared__ int s[512];
    int k = threadIdx.x;
    int v = (k < NBLK) ? part[k * NBUCKP + b] : 0;
    s[k] = v;
    __syncthreads();
    for (int off = 1; off < 512; off <<= 1) {
        int t = (k >= off) ? s[k - off] : 0;
        __syncthreads();
        s[k] += t;
        __syncthreads();
    }
    if (k < NBLK) part[k * NBUCKP + b] = s[k] - v;   // exclusive within bucket
    if (k == 511) tot[b] = s[511];
}

// ---- exclusive scan of bucket totals -> base ----
__global__ void bucket_base_final(const int* __restrict__ totS, const int* __restrict__ totD,
                                  int* __restrict__ baseS, int* __restrict__ baseD) {
    const int* tot = blockIdx.x ? totD : totS;
    int* base = blockIdx.x ? baseD : baseS;
    __shared__ int s[512];
    int k = threadIdx.x;
    int v = (k < NBUCK) ? tot[k] : 0;
    s[k] = v;
    __syncthreads();
    for (int off = 1; off < 512; off <<= 1) {
        int t = (k >= off) ? s[k - off] : 0;
        __syncthreads();
        s[k] += t;
        __syncthreads();
    }
    if (k < NBUCK) base[k] = s[k] - v;
    if (k == NBUCK - 1) base[NBUCK] = s[k];   // total == N_EDGES
}

// ---- pass B: scatter edges into bucket-grouped arrays; cursors = 2 coalesced loads ----
__global__ void bucket_scatter(const int* __restrict__ src, const int* __restrict__ dst,
                               const int* __restrict__ partS, const int* __restrict__ partD,
                               const int* __restrict__ baseS, const int* __restrict__ baseD,
                               unsigned int* __restrict__ packedD,
                               unsigned char* __restrict__ srcloc) {
    __shared__ int cS[NBUCK], cD[NBUCK];
    int blk = blockIdx.x;
    for (int b = threadIdx.x; b < NBUCK; b += blockDim.x) {
        cS[b] = baseS[b] + partS[blk * NBUCKP + b];
        cD[b] = baseD[b] + partD[blk * NBUCKP + b];
    }
    __syncthreads();
    const int4* s4 = (const int4*)(src + blk * EPB);
    const int4* d4 = (const int4*)(dst + blk * EPB);
    for (int k = threadIdx.x; k < EPB4; k += blockDim.x) {
        int4 sv = s4[k], dv = d4[k];
        int ss[4] = { sv.x, sv.y, sv.z, sv.w };
        int dd[4] = { dv.x, dv.y, dv.z, dv.w };
        #pragma unroll
        for (int u = 0; u < 4; ++u) {
            int s = ss[u], d = dd[u];
            int pD = atomicAdd(&cD[d >> BSH], 1);
            packedD[pD] = (unsigned)s | ((unsigned)(d & BMASK) << 16);
            int pS = atomicAdd(&cS[s >> BSH], 1);
            srcloc[pS] = (unsigned char)(s & BMASK);
        }
    }
}

// ---- per-bucket counting sort -> per-node CSR (col, rowptr) + src-degree -> dinv ----
__global__ void csr_build(const unsigned int* __restrict__ packedD, const int* __restrict__ baseD,
                          const unsigned char* __restrict__ srcloc, const int* __restrict__ baseS,
                          int* __restrict__ col, int* __restrict__ rowptr,
                          float* __restrict__ dinv) {
    __shared__ int hist[BNODES], scanv[BNODES], cur[BNODES], shist[BNODES];
    int tid = threadIdx.x;
    if (tid < BNODES) { hist[tid] = 0; shist[tid] = 0; }
    __syncthreads();
    int bb = blockIdx.x;
    int begD = baseD[bb], endD = baseD[bb + 1];
    for (int j = begD + tid; j < endD; j += blockDim.x)
        atomicAdd(&hist[(packedD[j] >> 16) & BMASK], 1);
    int begS = baseS[bb], endS = baseS[bb + 1];
    for (int j = begS + tid; j < endS; j += blockDim.x)
        atomicAdd(&shist[srcloc[j]], 1);
    __syncthreads();
    if (tid == 0) {
        int acc = 0;
        for (int i = 0; i < BNODES; ++i) { scanv[i] = acc; acc += hist[i]; }
    }
    __syncthreads();
    if (tid < BNODES) {
        cur[tid] = scanv[tid];
        int node = bb * BNODES + tid;
        if (node < N_NODES) {
            rowptr[node] = begD + scanv[tid];
            int d = shist[tid];
            dinv[node] = (d > 0) ? rsqrtf((float)d) : 0.0f;
        }
    }
    if (bb == NBUCK - 1 && tid == 0) rowptr[N_NODES] = endD;   // == N_EDGES
    __syncthreads();
    for (int j = begD + tid; j < endD; j += blockDim.x) {
        unsigned rec = packedD[j];
        int dl = (rec >> 16) & BMASK;
        int pos = atomicAdd(&cur[dl], 1);
        col[begD + pos] = (int)(rec & 0xFFFF);   // global src id (fits 16b: N<65536)
    }
}

// ---- xw0 = x@W1[0]; sxw1 = dinv * (x@W1[1]) ----
__global__ void xw_kernel(const float* __restrict__ x, const float* __restrict__ W1,
                          const float* __restrict__ dinv,
                          float* __restrict__ xw0, float* __restrict__ sxw1) {
    __shared__ float sW[2 * D_IN * H_HID];   // 8 KB
    __shared__ float sx[16 * 65];
    for (int i = threadIdx.x; i < 2 * D_IN * H_HID; i += 256) sW[i] = W1[i];
    int nbase = blockIdx.x * 16;
    for (int i = threadIdx.x; i < 16 * D_IN; i += 256) {
        int r = i >> 6, c = i & 63;
        sx[r * 65 + c] = x[(size_t)(nbase + r) * D_IN + c];
    }
    __syncthreads();
    int nl = threadIdx.x >> 4, f = threadIdx.x & 15;
    int node = nbase + nl;                    // N = 3125*16 exactly
    float a0 = 0.f, a1 = 0.f;
    #pragma unroll
    for (int d = 0; d < D_IN; ++d) {
        float xv = sx[nl * 65 + d];
        a0 += xv * sW[d * H_HID + f];
        a1 += xv * sW[D_IN * H_HID + d * H_HID + f];
    }
    int t = node * H_HID + f;
    xw0[t]  = a0;
    sxw1[t] = dinv[node] * a1;
}

// ---- layer-1 gather: 8 lanes per node (float2/lane), 8-deep unroll ----
__global__ void gather1(const int* __restrict__ rowptr, const int* __restrict__ col,
                        const float* __restrict__ dinv, const float* __restrict__ sxw1,
                        const float* __restrict__ xw0, const float* __restrict__ b1,
                        float* __restrict__ h, float* __restrict__ sh) {
    int grp = threadIdx.x >> 3;               // 64 groups per 512-thread block
    int f2  = threadIdx.x & 7;                // feature pair index
    int node = blockIdx.x * 64 + grp;
    if (node >= N_NODES) return;
    int beg = rowptr[node], end = rowptr[node + 1];
    const float2* sx2 = (const float2*)sxw1;
    float ax = 0.f, ay = 0.f;
    int j = beg;
    for (; j + 8 <= end; j += 8) {            // 8 independent 8B gathers in flight
        int c0 = col[j],     c1 = col[j + 1], c2 = col[j + 2], c3 = col[j + 3];
        int c4 = col[j + 4], c5 = col[j + 5], c6 = col[j + 6], c7 = col[j + 7];
        float2 v0 = sx2[c0 * 8 + f2], v1 = sx2[c1 * 8 + f2];
        float2 v2 = sx2[c2 * 8 + f2], v3 = sx2[c3 * 8 + f2];
        float2 v4 = sx2[c4 * 8 + f2], v5 = sx2[c5 * 8 + f2];
        float2 v6 = sx2[c6 * 8 + f2], v7 = sx2[c7 * 8 + f2];
        ax += ((v0.x + v1.x) + (v2.x + v3.x)) + ((v4.x + v5.x) + (v6.x + v7.x));
        ay += ((v0.y + v1.y) + (v2.y + v3.y)) + ((v4.y + v5.y) + (v6.y + v7.y));
    }
    for (; j < end; ++j) {
        float2 v = sx2[col[j] * 8 + f2];
        ax += v.x; ay += v.y;
    }
    float di = dinv[node];
    float2 x0 = ((const float2*)xw0)[node * 8 + f2];
    float2 bb = ((const float2*)b1)[f2];
    float vx = fmaxf(x0.x - di * ax + bb.x, 0.f);
    float vy = fmaxf(x0.y - di * ay + bb.y, 0.f);
    ((float2*)h)[node * 8 + f2]  = make_float2(vx, vy);
    ((float2*)sh)[node * 8 + f2] = make_float2(di * vx, di * vy);
}

// ---- layer-2 gather FUSED with dual matmul + log_softmax ----
// 8 lanes/node accumulate t1 pair; rows exchanged via LDS (wave-internal);
// each lane then computes 5 classes; softmax via 8-lane-group shfl reduce.
__global__ void gather2_out(const int* __restrict__ rowptr, const int* __restrict__ col,
                            const float* __restrict__ dinv, const float* __restrict__ sh,
                            const float* __restrict__ h, const float* __restrict__ W2,
                            const float* __restrict__ b2, float* __restrict__ out) {
    __shared__ float sW0[H_HID * C_OUT], sW1[H_HID * C_OUT], sb[C_OUT];
    __shared__ float hrow[64][H_HID];    // 4 KB
    __shared__ float trow[64][H_HID];    // 4 KB
    for (int i = threadIdx.x; i < H_HID * C_OUT; i += 512) {
        sW0[i] = W2[i];
        sW1[i] = W2[H_HID * C_OUT + i];
    }
    if (threadIdx.x < C_OUT) sb[threadIdx.x] = b2[threadIdx.x];

    int grp = threadIdx.x >> 3;
    int f2  = threadIdx.x & 7;
    int node = blockIdx.x * 64 + grp;
    bool active = node < N_NODES;
    int beg = 0, end = 0;
    float di = 0.f;
    if (active) { beg = rowptr[node]; end = rowptr[node + 1]; di = dinv[node]; }
    const float2* sh2 = (const float2*)sh;
    float ax = 0.f, ay = 0.f;
    int j = beg;
    for (; j + 8 <= end; j += 8) {
        int c0 = col[j],     c1 = col[j + 1], c2 = col[j + 2], c3 = col[j + 3];
        int c4 = col[j + 4], c5 = col[j + 5], c6 = col[j + 6], c7 = col[j + 7];
        float2 v0 = sh2[c0 * 8 + f2], v1 = sh2[c1 * 8 + f2];
        float2 v2 = sh2[c2 * 8 + f2], v3 = sh2[c3 * 8 + f2];
        float2 v4 = sh2[c4 * 8 + f2], v5 = sh2[c5 * 8 + f2];
        float2 v6 = sh2[c6 * 8 + f2], v7 = sh2[c7 * 8 + f2];
        ax += ((v0.x + v1.x) + (v2.x + v3.x)) + ((v4.x + v5.x) + (v6.x + v7.x));
        ay += ((v0.y + v1.y) + (v2.y + v3.y)) + ((v4.y + v5.y) + (v6.y + v7.y));
    }
    for (; j < end; ++j) {
        float2 v = sh2[col[j] * 8 + f2];
        ax += v.x; ay += v.y;
    }
    float2 hp = make_float2(0.f, 0.f);
    if (active) hp = ((const float2*)h)[node * 8 + f2];
    hrow[grp][2 * f2]     = hp.x;
    hrow[grp][2 * f2 + 1] = hp.y;
    trow[grp][2 * f2]     = -di * ax;
    trow[grp][2 * f2 + 1] = -di * ay;
    __syncthreads();

    float hv[H_HID], tv[H_HID];
    #pragma unroll
    for (int q = 0; q < 4; ++q) {
        float4 a = ((const float4*)hrow[grp])[q];
        float4 b = ((const float4*)trow[grp])[q];
        hv[q*4+0] = a.x; hv[q*4+1] = a.y; hv[q*4+2] = a.z; hv[q*4+3] = a.w;
        tv[q*4+0] = b.x; tv[q*4+1] = b.y; tv[q*4+2] = b.z; tv[q*4+3] = b.w;
    }
    float o[5];
    float mx = -1e30f;
    #pragma unroll
    for (int i = 0; i < 5; ++i) {
        int c = f2 * 5 + i;
        float a = sb[c];
        #pragma unroll
        for (int ff = 0; ff < H_HID; ++ff)
            a += hv[ff] * sW0[ff * C_OUT + c] + tv[ff] * sW1[ff * C_OUT + c];
        o[i] = a;
        mx = fmaxf(mx, a);
    }
    mx = fmaxf(mx, __shfl_xor(mx, 1));
    mx = fmaxf(mx, __shfl_xor(mx, 2));
    mx = fmaxf(mx, __shfl_xor(mx, 4));
    float sum = 0.f;
    #pragma unroll
    for (int i = 0; i < 5; ++i) sum += expf(o[i] - mx);
    sum += __shfl_xor(sum, 1);
    sum += __shfl_xor(sum, 2);
    sum += __shfl_xor(sum, 4);
    float lse = mx + logf(sum);
    if (active) {
        float* op = out + (size_t)node * C_OUT + f2 * 5;
        #pragma unroll
        for (int i = 0; i < 5; ++i) op[i] = o[i] - lse;
    }
}

extern "C" void kernel_launch(void* const* d_in, const int* in_sizes, int n_in,
                              void* d_out, int out_size, void* d_ws, size_t ws_size,
                              hipStream_t stream) {
    const float* x   = (const float*)d_in[0];
    const int*   ei  = (const int*)d_in[1];
    const float* W1  = (const float*)d_in[2];
    const float* b1  = (const float*)d_in[3];
    const float* W2  = (const float*)d_in[4];
    const float* b2  = (const float*)d_in[5];
    float* out = (float*)d_out;

    const int* src = ei;            // edge_index[0]
    const int* dst = ei + N_EDGES;  // edge_index[1]

    // workspace layout
    int* partS = (int*)d_ws;                                      // NBLK*NBUCKP
    int* partD = partS + NBLK * NBUCKP;                           // NBLK*NBUCKP
    int* baseS = partD + NBLK * NBUCKP;                           // NBUCK+1 (pad 512)
    int* baseD = baseS + 512;                                     // NBUCK+1 (pad 512)
    int* totS  = baseD + 512;                                     // NBUCK (pad 512)
    int* totD  = totS + 512;                                      // NBUCK (pad 512)
    unsigned int*  packedD = (unsigned int*)(totD + 512);         // E
    unsigned char* srcloc  = (unsigned char*)(packedD + N_EDGES); // E bytes
    int*   col    = (int*)(srcloc + N_EDGES);                     // E
    int*   rowptr = col + N_EDGES;                                // N+1 (pad)
    float* dinv   = (float*)(rowptr + N_NODES + 8);               // N
    float* xw0    = dinv + N_NODES;                               // N*16
    float* sxw1   = xw0  + (size_t)N_NODES * H_HID;               // N*16
    float* h      = sxw1 + (size_t)N_NODES * H_HID;               // N*16
    float* sh     = h    + (size_t)N_NODES * H_HID;               // N*16

    bucket_count    <<<NBLK, 256, 0, stream>>>(src, dst, partS, partD);
    bucket_base_scan<<<dim3(NBUCK, 2), 512, 0, stream>>>(partS, partD, totS, totD);
    bucket_base_final<<<2, 512, 0, stream>>>(totS, totD, baseS, baseD);
    bucket_scatter  <<<NBLK, 256, 0, stream>>>(src, dst, partS, partD, baseS, baseD, packedD, srcloc);
    csr_build       <<<NBUCK, 512, 0, stream>>>(packedD, baseD, srcloc, baseS, col, rowptr, dinv);
    xw_kernel       <<<N_NODES / 16, 256, 0, stream>>>(x, W1, dinv, xw0, sxw1);
    gather1         <<<(N_NODES + 63) / 64, 512, 0, stream>>>(rowptr, col, dinv, sxw1, xw0, b1, h, sh);
    gather2_out     <<<(N_NODES + 63) / 64, 512, 0, stream>>>(rowptr, col, dinv, sh, h, W2, b2, out);
}

// Round 11
// 90.350 us; speedup vs baseline: 3.5002x; 1.0547x over previous
//
#include <hip/hip_runtime.h>
#include <math.h>

#define N_NODES 50000
#define N_EDGES 800000
#define D_IN    64
#define H_HID   16
#define C_OUT   40

#define BSH     7                                  // 128 nodes per bucket
#define BNODES  128
#define BMASK   127
#define NBUCK   ((N_NODES + BNODES - 1) / BNODES)  // 391
#define NBUCKP  400                                // padded stride for part arrays
#define NBLK    500                                // edge slabs
#define EPB     (N_EDGES / NBLK)                   // 1600 exact, 16B-aligned
#define EPB4    (EPB / 4)                          // 400 int4s per slab

// ---- pass A: per-(block,bucket) histograms, LDS only; part[block][bucket] ----
__global__ void bucket_count(const int* __restrict__ src, const int* __restrict__ dst,
                             int* __restrict__ partS, int* __restrict__ partD) {
    __shared__ int hS[NBUCK], hD[NBUCK];
    for (int i = threadIdx.x; i < NBUCK; i += blockDim.x) { hS[i] = 0; hD[i] = 0; }
    __syncthreads();
    const int4* s4 = (const int4*)(src + blockIdx.x * EPB);
    const int4* d4 = (const int4*)(dst + blockIdx.x * EPB);
    for (int k = threadIdx.x; k < EPB4; k += blockDim.x) {
        int4 s = s4[k], d = d4[k];
        atomicAdd(&hS[s.x >> BSH], 1); atomicAdd(&hS[s.y >> BSH], 1);
        atomicAdd(&hS[s.z >> BSH], 1); atomicAdd(&hS[s.w >> BSH], 1);
        atomicAdd(&hD[d.x >> BSH], 1); atomicAdd(&hD[d.y >> BSH], 1);
        atomicAdd(&hD[d.z >> BSH], 1); atomicAdd(&hD[d.w >> BSH], 1);
    }
    __syncthreads();
    for (int i = threadIdx.x; i < NBUCK; i += blockDim.x) {
        partS[blockIdx.x * NBUCKP + i] = hS[i];
        partD[blockIdx.x * NBUCKP + i] = hD[i];
    }
}

// ---- prefix over blocks, one block per (bucket, S/D): part[k][b] <- sum_{k'<k} ----
__global__ void bucket_base_scan(int* __restrict__ partS, int* __restrict__ partD,
                                 int* __restrict__ totS, int* __restrict__ totD) {
    int* part = blockIdx.y ? partD : partS;
    int* tot  = blockIdx.y ? totD  : totS;
    int b = blockIdx.x;
    __shared__ int s[512];
    int k = threadIdx.x;
    int v = (k < NBLK) ? part[k * NBUCKP + b] : 0;
    s[k] = v;
    __syncthreads();
    for (int off = 1; off < 512; off <<= 1) {
        int t = (k >= off) ? s[k - off] : 0;
        __syncthreads();
        s[k] += t;
        __syncthreads();
    }
    if (k < NBLK) part[k * NBUCKP + b] = s[k] - v;   // exclusive within bucket
    if (k == 511) tot[b] = s[511];
}

// ---- exclusive scan of bucket totals -> base ----
__global__ void bucket_base_final(const int* __restrict__ totS, const int* __restrict__ totD,
                                  int* __restrict__ baseS, int* __restrict__ baseD) {
    const int* tot = blockIdx.x ? totD : totS;
    int* base = blockIdx.x ? baseD : baseS;
    __shared__ int s[512];
    int k = threadIdx.x;
    int v = (k < NBUCK) ? tot[k] : 0;
    s[k] = v;
    __syncthreads();
    for (int off = 1; off < 512; off <<= 1) {
        int t = (k >= off) ? s[k - off] : 0;
        __syncthreads();
        s[k] += t;
        __syncthreads();
    }
    if (k < NBUCK) base[k] = s[k] - v;
    if (k == NBUCK - 1) base[NBUCK] = s[k];   // total == N_EDGES
}

// ---- pass B: scatter edges into bucket-grouped arrays; cursors = 2 coalesced loads ----
__global__ void bucket_scatter(const int* __restrict__ src, const int* __restrict__ dst,
                               const int* __restrict__ partS, const int* __restrict__ partD,
                               const int* __restrict__ baseS, const int* __restrict__ baseD,
                               unsigned int* __restrict__ packedD,
                               unsigned char* __restrict__ srcloc) {
    __shared__ int cS[NBUCK], cD[NBUCK];
    int blk = blockIdx.x;
    for (int b = threadIdx.x; b < NBUCK; b += blockDim.x) {
        cS[b] = baseS[b] + partS[blk * NBUCKP + b];
        cD[b] = baseD[b] + partD[blk * NBUCKP + b];
    }
    __syncthreads();
    const int4* s4 = (const int4*)(src + blk * EPB);
    const int4* d4 = (const int4*)(dst + blk * EPB);
    for (int k = threadIdx.x; k < EPB4; k += blockDim.x) {
        int4 sv = s4[k], dv = d4[k];
        int ss[4] = { sv.x, sv.y, sv.z, sv.w };
        int dd[4] = { dv.x, dv.y, dv.z, dv.w };
        #pragma unroll
        for (int u = 0; u < 4; ++u) {
            int s = ss[u], d = dd[u];
            int pD = atomicAdd(&cD[d >> BSH], 1);
            packedD[pD] = (unsigned)s | ((unsigned)(d & BMASK) << 16);
            int pS = atomicAdd(&cS[s >> BSH], 1);
            srcloc[pS] = (unsigned char)(s & BMASK);
        }
    }
}

// ---- per-bucket counting sort -> per-node CSR (col, rowptr) + src-degree -> dinv ----
__global__ void csr_build(const unsigned int* __restrict__ packedD, const int* __restrict__ baseD,
                          const unsigned char* __restrict__ srcloc, const int* __restrict__ baseS,
                          int* __restrict__ col, int* __restrict__ rowptr,
                          float* __restrict__ dinv) {
    __shared__ int hist[BNODES], scanv[BNODES], cur[BNODES], shist[BNODES];
    int tid = threadIdx.x;
    if (tid < BNODES) { hist[tid] = 0; shist[tid] = 0; }
    __syncthreads();
    int bb = blockIdx.x;
    int begD = baseD[bb], endD = baseD[bb + 1];
    for (int j = begD + tid; j < endD; j += blockDim.x)
        atomicAdd(&hist[(packedD[j] >> 16) & BMASK], 1);
    int begS = baseS[bb], endS = baseS[bb + 1];
    for (int j = begS + tid; j < endS; j += blockDim.x)
        atomicAdd(&shist[srcloc[j]], 1);
    __syncthreads();
    if (tid == 0) {
        int acc = 0;
        for (int i = 0; i < BNODES; ++i) { scanv[i] = acc; acc += hist[i]; }
    }
    __syncthreads();
    if (tid < BNODES) {
        cur[tid] = scanv[tid];
        int node = bb * BNODES + tid;
        if (node < N_NODES) {
            rowptr[node] = begD + scanv[tid];
            int d = shist[tid];
            dinv[node] = (d > 0) ? rsqrtf((float)d) : 0.0f;
        }
    }
    if (bb == NBUCK - 1 && tid == 0) rowptr[N_NODES] = endD;   // == N_EDGES
    __syncthreads();
    for (int j = begD + tid; j < endD; j += blockDim.x) {
        unsigned rec = packedD[j];
        int dl = (rec >> 16) & BMASK;
        int pos = atomicAdd(&cur[dl], 1);
        col[begD + pos] = (int)(rec & 0xFFFF);   // global src id (fits 16b: N<65536)
    }
}

// ---- xw0 = x@W1[0]; sxw1 = dinv * (x@W1[1]) ----
__global__ void xw_kernel(const float* __restrict__ x, const float* __restrict__ W1,
                          const float* __restrict__ dinv,
                          float* __restrict__ xw0, float* __restrict__ sxw1) {
    __shared__ float sW[2 * D_IN * H_HID];   // 8 KB
    __shared__ float sx[16 * 65];
    for (int i = threadIdx.x; i < 2 * D_IN * H_HID; i += 256) sW[i] = W1[i];
    int nbase = blockIdx.x * 16;
    for (int i = threadIdx.x; i < 16 * D_IN; i += 256) {
        int r = i >> 6, c = i & 63;
        sx[r * 65 + c] = x[(size_t)(nbase + r) * D_IN + c];
    }
    __syncthreads();
    int nl = threadIdx.x >> 4, f = threadIdx.x & 15;
    int node = nbase + nl;                    // N = 3125*16 exactly
    float a0 = 0.f, a1 = 0.f;
    #pragma unroll
    for (int d = 0; d < D_IN; ++d) {
        float xv = sx[nl * 65 + d];
        a0 += xv * sW[d * H_HID + f];
        a1 += xv * sW[D_IN * H_HID + d * H_HID + f];
    }
    int t = node * H_HID + f;
    xw0[t]  = a0;
    sxw1[t] = dinv[node] * a1;
}

// ---- layer-1 gather: 4 lanes per node (float4/lane), 16 nodes/wave, 8-deep unroll ----
__global__ void gather1(const int* __restrict__ rowptr, const int* __restrict__ col,
                        const float* __restrict__ dinv, const float* __restrict__ sxw1,
                        const float* __restrict__ xw0, const float* __restrict__ b1,
                        float* __restrict__ h, float* __restrict__ sh) {
    int grp = threadIdx.x >> 2;               // 128 groups per 512-thread block
    int f4  = threadIdx.x & 3;                // float4 slot (4 feats per lane)
    int node = blockIdx.x * 128 + grp;
    if (node >= N_NODES) return;
    int beg = rowptr[node], end = rowptr[node + 1];
    const float4* sx4 = (const float4*)sxw1;
    float4 a = make_float4(0.f, 0.f, 0.f, 0.f);
    int j = beg;
    for (; j + 8 <= end; j += 8) {            // 8 independent 16B gathers in flight
        int c0 = col[j],     c1 = col[j + 1], c2 = col[j + 2], c3 = col[j + 3];
        int c4 = col[j + 4], c5 = col[j + 5], c6 = col[j + 6], c7 = col[j + 7];
        float4 v0 = sx4[c0 * 4 + f4], v1 = sx4[c1 * 4 + f4];
        float4 v2 = sx4[c2 * 4 + f4], v3 = sx4[c3 * 4 + f4];
        float4 v4 = sx4[c4 * 4 + f4], v5 = sx4[c5 * 4 + f4];
        float4 v6 = sx4[c6 * 4 + f4], v7 = sx4[c7 * 4 + f4];
        a.x += ((v0.x + v1.x) + (v2.x + v3.x)) + ((v4.x + v5.x) + (v6.x + v7.x));
        a.y += ((v0.y + v1.y) + (v2.y + v3.y)) + ((v4.y + v5.y) + (v6.y + v7.y));
        a.z += ((v0.z + v1.z) + (v2.z + v3.z)) + ((v4.z + v5.z) + (v6.z + v7.z));
        a.w += ((v0.w + v1.w) + (v2.w + v3.w)) + ((v4.w + v5.w) + (v6.w + v7.w));
    }
    for (; j < end; ++j) {
        float4 v = sx4[col[j] * 4 + f4];
        a.x += v.x; a.y += v.y; a.z += v.z; a.w += v.w;
    }
    float di = dinv[node];
    float4 x0 = ((const float4*)xw0)[node * 4 + f4];
    float4 bb = ((const float4*)b1)[f4];
    float vx = fmaxf(x0.x - di * a.x + bb.x, 0.f);
    float vy = fmaxf(x0.y - di * a.y + bb.y, 0.f);
    float vz = fmaxf(x0.z - di * a.z + bb.z, 0.f);
    float vw = fmaxf(x0.w - di * a.w + bb.w, 0.f);
    ((float4*)h)[node * 4 + f4]  = make_float4(vx, vy, vz, vw);
    ((float4*)sh)[node * 4 + f4] = make_float4(di * vx, di * vy, di * vz, di * vw);
}

// ---- layer-2 gather FUSED with dual matmul + log_softmax (4-lane groups) ----
#define HROW 20   // padded row stride (floats) to break 64B bank aliasing
__global__ void gather2_out(const int* __restrict__ rowptr, const int* __restrict__ col,
                            const float* __restrict__ dinv, const float* __restrict__ sh,
                            const float* __restrict__ h, const float* __restrict__ W2,
                            const float* __restrict__ b2, float* __restrict__ out) {
    __shared__ float sW0[H_HID * C_OUT], sW1[H_HID * C_OUT], sb[C_OUT];
    __shared__ float hrow[128][HROW];    // 10 KB
    __shared__ float trow[128][HROW];    // 10 KB
    for (int i = threadIdx.x; i < H_HID * C_OUT; i += 512) {
        sW0[i] = W2[i];
        sW1[i] = W2[H_HID * C_OUT + i];
    }
    if (threadIdx.x < C_OUT) sb[threadIdx.x] = b2[threadIdx.x];

    int grp = threadIdx.x >> 2;
    int f4  = threadIdx.x & 3;
    int node = blockIdx.x * 128 + grp;
    bool active = node < N_NODES;
    int beg = 0, end = 0;
    float di = 0.f;
    if (active) { beg = rowptr[node]; end = rowptr[node + 1]; di = dinv[node]; }
    const float4* sh4 = (const float4*)sh;
    float4 a = make_float4(0.f, 0.f, 0.f, 0.f);
    int j = beg;
    for (; j + 8 <= end; j += 8) {
        int c0 = col[j],     c1 = col[j + 1], c2 = col[j + 2], c3 = col[j + 3];
        int c4 = col[j + 4], c5 = col[j + 5], c6 = col[j + 6], c7 = col[j + 7];
        float4 v0 = sh4[c0 * 4 + f4], v1 = sh4[c1 * 4 + f4];
        float4 v2 = sh4[c2 * 4 + f4], v3 = sh4[c3 * 4 + f4];
        float4 v4 = sh4[c4 * 4 + f4], v5 = sh4[c5 * 4 + f4];
        float4 v6 = sh4[c6 * 4 + f4], v7 = sh4[c7 * 4 + f4];
        a.x += ((v0.x + v1.x) + (v2.x + v3.x)) + ((v4.x + v5.x) + (v6.x + v7.x));
        a.y += ((v0.y + v1.y) + (v2.y + v3.y)) + ((v4.y + v5.y) + (v6.y + v7.y));
        a.z += ((v0.z + v1.z) + (v2.z + v3.z)) + ((v4.z + v5.z) + (v6.z + v7.z));
        a.w += ((v0.w + v1.w) + (v2.w + v3.w)) + ((v4.w + v5.w) + (v6.w + v7.w));
    }
    for (; j < end; ++j) {
        float4 v = sh4[col[j] * 4 + f4];
        a.x += v.x; a.y += v.y; a.z += v.z; a.w += v.w;
    }
    float4 hp = make_float4(0.f, 0.f, 0.f, 0.f);
    if (active) hp = ((const float4*)h)[node * 4 + f4];
    hrow[grp][4 * f4 + 0] = hp.x;
    hrow[grp][4 * f4 + 1] = hp.y;
    hrow[grp][4 * f4 + 2] = hp.z;
    hrow[grp][4 * f4 + 3] = hp.w;
    trow[grp][4 * f4 + 0] = -di * a.x;
    trow[grp][4 * f4 + 1] = -di * a.y;
    trow[grp][4 * f4 + 2] = -di * a.z;
    trow[grp][4 * f4 + 3] = -di * a.w;
    __syncthreads();

    float hv[H_HID], tv[H_HID];
    #pragma unroll
    for (int ff = 0; ff < H_HID; ++ff) {
        hv[ff] = hrow[grp][ff];
        tv[ff] = trow[grp][ff];
    }
    float o[10];
    float mx = -1e30f;
    #pragma unroll
    for (int i = 0; i < 10; ++i) {
        int c = f4 * 10 + i;
        float aa = sb[c];
        #pragma unroll
        for (int ff = 0; ff < H_HID; ++ff)
            aa += hv[ff] * sW0[ff * C_OUT + c] + tv[ff] * sW1[ff * C_OUT + c];
        o[i] = aa;
        mx = fmaxf(mx, aa);
    }
    mx = fmaxf(mx, __shfl_xor(mx, 1));
    mx = fmaxf(mx, __shfl_xor(mx, 2));
    float sum = 0.f;
    #pragma unroll
    for (int i = 0; i < 10; ++i) sum += expf(o[i] - mx);
    sum += __shfl_xor(sum, 1);
    sum += __shfl_xor(sum, 2);
    float lse = mx + logf(sum);
    if (active) {
        float* op = out + (size_t)node * C_OUT + f4 * 10;
        #pragma unroll
        for (int i = 0; i < 10; ++i) op[i] = o[i] - lse;
    }
}

extern "C" void kernel_launch(void* const* d_in, const int* in_sizes, int n_in,
                              void* d_out, int out_size, void* d_ws, size_t ws_size,
                              hipStream_t stream) {
    const float* x   = (const float*)d_in[0];
    const int*   ei  = (const int*)d_in[1];
    const float* W1  = (const float*)d_in[2];
    const float* b1  = (const float*)d_in[3];
    const float* W2  = (const float*)d_in[4];
    const float* b2  = (const float*)d_in[5];
    float* out = (float*)d_out;

    const int* src = ei;            // edge_index[0]
    const int* dst = ei + N_EDGES;  // edge_index[1]

    // workspace layout
    int* partS = (int*)d_ws;                                      // NBLK*NBUCKP
    int* partD = partS + NBLK * NBUCKP;                           // NBLK*NBUCKP
    int* baseS = partD + NBLK * NBUCKP;                           // NBUCK+1 (pad 512)
    int* baseD = baseS + 512;                                     // NBUCK+1 (pad 512)
    int* totS  = baseD + 512;                                     // NBUCK (pad 512)
    int* totD  = totS + 512;                                      // NBUCK (pad 512)
    unsigned int*  packedD = (unsigned int*)(totD + 512);         // E
    unsigned char* srcloc  = (unsigned char*)(packedD + N_EDGES); // E bytes
    int*   col    = (int*)(srcloc + N_EDGES);                     // E
    int*   rowptr = col + N_EDGES;                                // N+1 (pad)
    float* dinv   = (float*)(rowptr + N_NODES + 8);               // N
    float* xw0    = dinv + N_NODES;                               // N*16
    float* sxw1   = xw0  + (size_t)N_NODES * H_HID;               // N*16
    float* h      = sxw1 + (size_t)N_NODES * H_HID;               // N*16
    float* sh     = h    + (size_t)N_NODES * H_HID;               // N*16

    bucket_count    <<<NBLK, 256, 0, stream>>>(src, dst, partS, partD);
    bucket_base_scan<<<dim3(NBUCK, 2), 512, 0, stream>>>(partS, partD, totS, totD);
    bucket_base_final<<<2, 512, 0, stream>>>(totS, totD, baseS, baseD);
    bucket_scatter  <<<NBLK, 256, 0, stream>>>(src, dst, partS, partD, baseS, baseD, packedD, srcloc);
    csr_build       <<<NBUCK, 512, 0, stream>>>(packedD, baseD, srcloc, baseS, col, rowptr, dinv);
    xw_kernel       <<<N_NODES / 16, 256, 0, stream>>>(x, W1, dinv, xw0, sxw1);
    gather1         <<<(N_NODES + 127) / 128, 512, 0, stream>>>(rowptr, col, dinv, sxw1, xw0, b1, h, sh);
    gather2_out     <<<(N_NODES + 127) / 128, 512, 0, stream>>>(rowptr, col, dinv, sh, h, W2, b2, out);
}